// Round 3
// baseline (1332.604 us; speedup 1.0000x reference)
//
#include <hip/hip_runtime.h>
#include <math.h>

// Problem constants (match reference)
namespace {
constexpr int B_   = 8;
constexpr int M_   = 512;
constexpr int N_   = 1024;
constexpr int DTS  = 1024;
constexpr int DLLM = 4096;
constexpr int H_   = 16;
constexpr int E_   = 64;
constexpr int HE   = H_ * E_;   // 1024
// Finite stand-in for -inf in scores_for_log.
constexpr float NEG_BIG = -3.0e38f;
}

typedef __attribute__((ext_vector_type(4))) float f32x4;
typedef __attribute__((ext_vector_type(8))) short short8;
typedef unsigned int uint;
typedef unsigned short ushort;

// RNE split x = hi + lo (both representable as bf16; lo truncated).
__device__ inline void bsplit(float x, ushort& h, ushort& l) {
  uint u = __float_as_uint(x);
  uint hr = (u + 0x7FFFu + ((u >> 16) & 1u)) & 0xFFFF0000u;
  float lof = x - __uint_as_float(hr);
  h = (ushort)(hr >> 16);
  l = (ushort)(__float_as_uint(lof) >> 16);
}
__device__ inline uint pk(ushort a, ushort b) { return (uint)a | ((uint)b << 16); }

// async 16B global->LDS (m97-verified path)
__device__ inline void gld16(const void* g, void* l) {
  __builtin_amdgcn_global_load_lds(
      (const __attribute__((address_space(1))) uint*)g,
      (__attribute__((address_space(3))) uint*)l, 16, 0, 0);
}

// ---------------------------------------------------------------------------
// One-shot elementwise fp32 -> bf16 hi/lo split (row-major, no transpose).
// ---------------------------------------------------------------------------
__global__ __launch_bounds__(256) void asplit_kernel(
    const float* __restrict__ X, ushort* __restrict__ Xh,
    ushort* __restrict__ Xl, int n8) {
  const int idx = blockIdx.x * 256 + threadIdx.x;
  if (idx >= n8) return;
  const float4 a = *(const float4*)(X + (size_t)idx * 8);
  const float4 b = *(const float4*)(X + (size_t)idx * 8 + 4);
  float f[8] = {a.x, a.y, a.z, a.w, b.x, b.y, b.z, b.w};
  short8 h, l;
#pragma unroll
  for (int j = 0; j < 8; ++j) {
    ushort hh, ll;
    bsplit(f[j], hh, ll);
    h[j] = (short)hh;
    l[j] = (short)ll;
  }
  *(short8*)(Xh + (size_t)idx * 8) = h;
  *(short8*)(Xl + (size_t)idx * 8) = l;
}

// ---------------------------------------------------------------------------
// Weight transpose + bf16 split: W fp32 [K][N] -> Wth, Wtl bf16 [N][K].
// ---------------------------------------------------------------------------
__global__ __launch_bounds__(256) void tsplit_kernel(
    const float* __restrict__ W, ushort* __restrict__ Wth,
    ushort* __restrict__ Wtl, int K, int Nc) {
  __shared__ float S[32][33];
  const int t = threadIdx.x;
  const int n0 = blockIdx.x * 32, k0 = blockIdx.y * 32;
  const int c = t & 31, r8 = t >> 5;
#pragma unroll
  for (int i = 0; i < 4; ++i) {
    const int rr = r8 + i * 8;
    S[rr][c] = W[(size_t)(k0 + rr) * Nc + n0 + c];
  }
  __syncthreads();
#pragma unroll
  for (int i = 0; i < 4; ++i) {
    const int nn = r8 + i * 8;
    const float x = S[c][nn];
    ushort h, l;
    bsplit(x, h, l);
    const size_t o = (size_t)(n0 + nn) * K + k0 + c;
    Wth[o] = h;
    Wtl[o] = l;
  }
}

// ---------------------------------------------------------------------------
// V transpose prep: V fp32 [b*n][HE] -> Vth/Vtl bf16 [(b*H+h)*64+e][N].
// ---------------------------------------------------------------------------
__global__ __launch_bounds__(256) void vtprep_kernel(
    const float* __restrict__ V, ushort* __restrict__ Vth,
    ushort* __restrict__ Vtl) {
  __shared__ float S[64][68];
  const int t  = threadIdx.x;
  const int nt = blockIdx.x & 15;
  const int h  = (blockIdx.x >> 4) & 15;
  const int b  = blockIdx.x >> 8;
  const int n0 = nt * 64;
#pragma unroll
  for (int i = 0; i < 4; ++i) {
    const int idx = i * 256 + t;
    const int row = idx >> 4, c4 = (idx & 15) * 4;
    *(float4*)&S[row][c4] =
        *(const float4*)&V[(size_t)(b * N_ + n0 + row) * HE + h * 64 + c4];
  }
  __syncthreads();
  const int e = t >> 2, nch = (t & 3) * 16;
  short8 h0, h1, l0, l1;
#pragma unroll
  for (int j = 0; j < 8; ++j) {
    ushort hh, ll;
    bsplit(S[nch + j][e], hh, ll);
    h0[j] = (short)hh; l0[j] = (short)ll;
    bsplit(S[nch + 8 + j][e], hh, ll);
    h1[j] = (short)hh; l1[j] = (short)ll;
  }
  const size_t off = (size_t)((b * H_ + h) * 64 + e) * N_ + n0 + nch;
  *(short8*)(Vth + off)     = h0;
  *(short8*)(Vth + off + 8) = h1;
  *(short8*)(Vtl + off)     = l0;
  *(short8*)(Vtl + off + 8) = l1;
}

// ---------------------------------------------------------------------------
// bf16x3 split MFMA GEMM, fp32 A converted in-loop (verified fallback path).
// ---------------------------------------------------------------------------
template <bool ROWMASK, bool SPLITOUT>
__global__ __launch_bounds__(256) void gemm_split3_kernel(
    const float* __restrict__ A, const ushort* __restrict__ Bth,
    const ushort* __restrict__ Btl, const float* __restrict__ bias,
    const float* __restrict__ rowmask, float* __restrict__ C,
    ushort* __restrict__ Ch, ushort* __restrict__ Cl, int Kd, int Nc) {
  __shared__ ushort Ah[128][32];
  __shared__ ushort Al[128][32];
  __shared__ ushort Bh[128][32];
  __shared__ ushort Bl[128][32];

  const int t    = threadIdx.x;
  const int lane = t & 63;
  const int wv   = t >> 6;
  const int l15  = lane & 15;
  const int quad = lane >> 4;
  const int wm   = (wv & 1) * 64;
  const int wn   = (wv >> 1) * 64;
  const int row0 = blockIdx.y * 128;
  const int col0 = blockIdx.x * 128;

  const int arow = t >> 1;
  const int half = t & 1;
  const float* Ap = A + (size_t)(row0 + arow) * Kd + half * 16;

  const int bn  = (lane >> 2);
  const int bk8 = (lane & 3) * 8;
  const ushort* Bhp = Bth + (size_t)(col0 + wv * 32 + bn) * Kd + bk8;
  const ushort* Blp = Btl + (size_t)(col0 + wv * 32 + bn) * Kd + bk8;

  f32x4 acc[4][4];
#pragma unroll
  for (int i = 0; i < 4; ++i)
#pragma unroll
    for (int j = 0; j < 4; ++j) acc[i][j] = {0.f, 0.f, 0.f, 0.f};

  for (int k0 = 0; k0 < Kd; k0 += 32) {
    __syncthreads();
#pragma unroll
    for (int j = 0; j < 2; ++j) {
      const int n = wv * 32 + j * 16 + bn;
      gld16(Bhp + (size_t)j * 16 * Kd + k0, &Bh[n][bk8]);
      gld16(Blp + (size_t)j * 16 * Kd + k0, &Bl[n][bk8]);
    }
    float f[16];
#pragma unroll
    for (int i = 0; i < 4; ++i) {
      const float4 v = *(const float4*)(Ap + k0 + i * 4);
      f[i * 4 + 0] = v.x; f[i * 4 + 1] = v.y;
      f[i * 4 + 2] = v.z; f[i * 4 + 3] = v.w;
    }
    ushort hh[16], ll[16];
#pragma unroll
    for (int i = 0; i < 16; ++i) bsplit(f[i], hh[i], ll[i]);
    uint4 wh0 = {pk(hh[0], hh[1]), pk(hh[2], hh[3]), pk(hh[4], hh[5]), pk(hh[6], hh[7])};
    uint4 wh1 = {pk(hh[8], hh[9]), pk(hh[10], hh[11]), pk(hh[12], hh[13]), pk(hh[14], hh[15])};
    uint4 wl0 = {pk(ll[0], ll[1]), pk(ll[2], ll[3]), pk(ll[4], ll[5]), pk(ll[6], ll[7])};
    uint4 wl1 = {pk(ll[8], ll[9]), pk(ll[10], ll[11]), pk(ll[12], ll[13]), pk(ll[14], ll[15])};
    *(uint4*)&Ah[arow][half * 16 + 0] = wh0;
    *(uint4*)&Ah[arow][half * 16 + 8] = wh1;
    *(uint4*)&Al[arow][half * 16 + 0] = wl0;
    *(uint4*)&Al[arow][half * 16 + 8] = wl1;

    __syncthreads();

    short8 ah[4], al[4], bh[4], bl[4];
#pragma unroll
    for (int mi = 0; mi < 4; ++mi) {
      ah[mi] = *(const short8*)&Ah[wm + mi * 16 + l15][quad * 8];
      al[mi] = *(const short8*)&Al[wm + mi * 16 + l15][quad * 8];
    }
#pragma unroll
    for (int ni = 0; ni < 4; ++ni) {
      bh[ni] = *(const short8*)&Bh[wn + ni * 16 + l15][quad * 8];
      bl[ni] = *(const short8*)&Bl[wn + ni * 16 + l15][quad * 8];
    }
#pragma unroll
    for (int mi = 0; mi < 4; ++mi)
#pragma unroll
      for (int ni = 0; ni < 4; ++ni) {
        acc[mi][ni] = __builtin_amdgcn_mfma_f32_16x16x32_bf16(
            ah[mi], bh[ni], acc[mi][ni], 0, 0, 0);
        acc[mi][ni] = __builtin_amdgcn_mfma_f32_16x16x32_bf16(
            ah[mi], bl[ni], acc[mi][ni], 0, 0, 0);
        acc[mi][ni] = __builtin_amdgcn_mfma_f32_16x16x32_bf16(
            al[mi], bh[ni], acc[mi][ni], 0, 0, 0);
      }
  }

  float bb[4];
#pragma unroll
  for (int ni = 0; ni < 4; ++ni) bb[ni] = bias[col0 + wn + ni * 16 + l15];
#pragma unroll
  for (int mi = 0; mi < 4; ++mi)
#pragma unroll
    for (int r = 0; r < 4; ++r) {
      const int row = row0 + wm + mi * 16 + quad * 4 + r;
      const float rm = ROWMASK ? rowmask[row] : 1.f;
#pragma unroll
      for (int ni = 0; ni < 4; ++ni) {
        const int col = col0 + wn + ni * 16 + l15;
        float v = acc[mi][ni][r] + bb[ni];
        if (SPLITOUT) {
          ushort vh, vl;
          bsplit(v, vh, vl);
          Ch[(size_t)row * Nc + col] = vh;
          Cl[(size_t)row * Nc + col] = vl;
        } else {
          if (ROWMASK) v *= rm;
          C[(size_t)row * Nc + col] = v;
        }
      }
    }
}

// ---------------------------------------------------------------------------
// bf16x3 split MFMA GEMM, BOTH operands pre-split bf16 hi/lo.
// A: [rows][Kd] (hi,lo). B: [Nc][Kd] transposed (hi,lo).
// R3 changes vs R2:
//  * 16B-chunk XOR swizzle (slot(row,ch) holds global chunk ch^(row&3)):
//    applied on per-lane GLOBAL source address (gld16 dest stays linear)
//    and on fragment reads -> bank-balanced ds_read_b128 (was ~8-way).
//  * Double-buffered LDS + 2-phase pipeline: issue next K-step's gld16,
//    compute current, single __syncthreads() per iteration (its implicit
//    vmcnt(0) drains the prefetch AFTER compute hid the latency).
// ---------------------------------------------------------------------------
template <bool ROWMASK, bool SPLITOUT>
__global__ __launch_bounds__(256) void gemm_bb_kernel(
    const ushort* __restrict__ Ath, const ushort* __restrict__ Atl,
    const ushort* __restrict__ Bth, const ushort* __restrict__ Btl,
    const float* __restrict__ bias, const float* __restrict__ rowmask,
    float* __restrict__ C, ushort* __restrict__ Ch, ushort* __restrict__ Cl,
    int Kd, int Nc) {
  __shared__ ushort Ah[2][128][32];   // 64 KB total -> 2 blocks/CU (grid-limited anyway)
  __shared__ ushort Al[2][128][32];
  __shared__ ushort Bh[2][128][32];
  __shared__ ushort Bl[2][128][32];

  const int t    = threadIdx.x;
  const int lane = t & 63;
  const int wv   = t >> 6;
  const int l15  = lane & 15;
  const int quad = lane >> 4;
  const int wm   = (wv & 1) * 64;
  const int wn   = (wv >> 1) * 64;
  const int row0 = blockIdx.y * 128;
  const int col0 = blockIdx.x * 128;

  // staging: one gld16 covers 16 rows x 64 B; lane -> (row srow, chunk lane&3),
  // global source chunk = (lane&3) ^ (srow&3)  (inverse-swizzled source, rule #21)
  const int srow = lane >> 2;                       // 0..15
  const int sch8 = ((lane & 3) ^ (srow & 3)) * 8;   // ushort offset of 16B chunk
  const ushort* Ahp = Ath + (size_t)(row0 + wv * 32 + srow) * Kd + sch8;
  const ushort* Alp = Atl + (size_t)(row0 + wv * 32 + srow) * Kd + sch8;
  const ushort* Bhp = Bth + (size_t)(col0 + wv * 32 + srow) * Kd + sch8;
  const ushort* Blp = Btl + (size_t)(col0 + wv * 32 + srow) * Kd + sch8;

  // fragment-read swizzle: chunk = quad ^ (row&3); row&3 == l15&3 here
  const int fsw = (quad ^ (l15 & 3)) * 8;           // ushort offset

  f32x4 acc[4][4];
#pragma unroll
  for (int i = 0; i < 4; ++i)
#pragma unroll
    for (int j = 0; j < 4; ++j) acc[i][j] = {0.f, 0.f, 0.f, 0.f};

  // prologue: stage k0=0 into buffer 0
#pragma unroll
  for (int j = 0; j < 2; ++j) {
    const int rr = wv * 32 + j * 16;
    const size_t o = (size_t)j * 16 * Kd;
    gld16(Ahp + o, &Ah[0][rr][0]);
    gld16(Alp + o, &Al[0][rr][0]);
    gld16(Bhp + o, &Bh[0][rr][0]);
    gld16(Blp + o, &Bl[0][rr][0]);
  }
  __syncthreads();

  int cur = 0;
  for (int k0 = 0; k0 < Kd; k0 += 32) {
    // issue next K-step's loads into the other buffer (overlaps compute)
    if (k0 + 32 < Kd) {
      const int nb = cur ^ 1;
#pragma unroll
      for (int j = 0; j < 2; ++j) {
        const int rr = wv * 32 + j * 16;
        const size_t o = (size_t)j * 16 * Kd + k0 + 32;
        gld16(Ahp + o, &Ah[nb][rr][0]);
        gld16(Alp + o, &Al[nb][rr][0]);
        gld16(Bhp + o, &Bh[nb][rr][0]);
        gld16(Blp + o, &Bl[nb][rr][0]);
      }
    }

    short8 ah[4], al[4], bh[4], bl[4];
#pragma unroll
    for (int mi = 0; mi < 4; ++mi) {
      const int row = wm + mi * 16 + l15;
      ah[mi] = *(const short8*)&Ah[cur][row][fsw];
      al[mi] = *(const short8*)&Al[cur][row][fsw];
    }
#pragma unroll
    for (int ni = 0; ni < 4; ++ni) {
      const int row = wn + ni * 16 + l15;
      bh[ni] = *(const short8*)&Bh[cur][row][fsw];
      bl[ni] = *(const short8*)&Bl[cur][row][fsw];
    }
#pragma unroll
    for (int mi = 0; mi < 4; ++mi)
#pragma unroll
      for (int ni = 0; ni < 4; ++ni) {
        acc[mi][ni] = __builtin_amdgcn_mfma_f32_16x16x32_bf16(
            ah[mi], bh[ni], acc[mi][ni], 0, 0, 0);
        acc[mi][ni] = __builtin_amdgcn_mfma_f32_16x16x32_bf16(
            ah[mi], bl[ni], acc[mi][ni], 0, 0, 0);
        acc[mi][ni] = __builtin_amdgcn_mfma_f32_16x16x32_bf16(
            al[mi], bh[ni], acc[mi][ni], 0, 0, 0);
      }

    __syncthreads();   // drains prefetch (vmcnt 0) + guards buffer reuse
    cur ^= 1;
  }

  float bb[4];
#pragma unroll
  for (int ni = 0; ni < 4; ++ni) bb[ni] = bias[col0 + wn + ni * 16 + l15];
#pragma unroll
  for (int mi = 0; mi < 4; ++mi)
#pragma unroll
    for (int r = 0; r < 4; ++r) {
      const int row = row0 + wm + mi * 16 + quad * 4 + r;
      const float rm = ROWMASK ? rowmask[row] : 1.f;
#pragma unroll
      for (int ni = 0; ni < 4; ++ni) {
        const int col = col0 + wn + ni * 16 + l15;
        float v = acc[mi][ni][r] + bb[ni];
        if (SPLITOUT) {
          ushort vh, vl;
          bsplit(v, vh, vl);
          Ch[(size_t)row * Nc + col] = vh;
          Cl[(size_t)row * Nc + col] = vl;
        } else {
          if (ROWMASK) v *= rm;
          C[(size_t)row * Nc + col] = v;
        }
      }
    }
}

// ---------------------------------------------------------------------------
// MFMA flash attention. Block = (b, h, 64 q-rows); 4 waves x 16 rows.
// ---------------------------------------------------------------------------
__global__ __launch_bounds__(256) void attn_mfma_kernel(
    const ushort* __restrict__ Qh, const ushort* __restrict__ Ql,
    const ushort* __restrict__ Kh, const ushort* __restrict__ Kl,
    const ushort* __restrict__ Vth, const ushort* __restrict__ Vtl,
    const unsigned char* __restrict__ kvmask, const float* __restrict__ tsmask,
    float* __restrict__ outv, float* __restrict__ scores_out) {
  __shared__ __align__(16) ushort sm[24576];  // 48 KB
  ushort* KHT = sm;            // [64 rows(n)][64 e] swizzled
  ushort* KLT = sm + 4096;
  ushort* VTH = sm + 8192;     // [64 rows(e)][64 n] swizzled
  ushort* VTL = sm + 12288;
  ushort* QHT = sm + 16384;    // [64 rows(m)][64 e] swizzled (dead after frag read)
  ushort* QLT = sm + 20480;

  const int t = threadIdx.x, lane = t & 63, wv = t >> 6;
  const int l15 = lane & 15, quad = lane >> 4;
  const int blk = blockIdx.x;          // b*128 + h*8 + mt
  const int mt = blk & 7;
  const int h  = (blk >> 3) & 15;
  const int b  = blk >> 7;
  const int m0 = mt * 64;
  const int lrow = lane >> 3, lch = lane & 7;
  const int gch8 = (lch ^ (lrow & 7)) * 8;  // swizzled 16B-chunk, ushort offset

  // ---- stage Q tile (wave wv: rows wv*16..+15), hi and lo ----
#pragma unroll
  for (int i = 0; i < 2; ++i) {
    const int rr = wv * 16 + i * 8;   // wave-uniform LDS row base
    const size_t g = (size_t)(b * M_ + m0 + rr + lrow) * HE + h * 64 + gch8;
    gld16(Qh + g, &QHT[rr * 64]);
    gld16(Ql + g, &QLT[rr * 64]);
  }
  __syncthreads();

  short8 qh[2], ql[2];
#pragma unroll
  for (int ks = 0; ks < 2; ++ks) {
    const int row = wv * 16 + l15;
    const int off = row * 64 + (((ks * 4 + quad) ^ (row & 7)) << 3);
    qh[ks] = *(const short8*)&QHT[off];
    ql[ks] = *(const short8*)&QLT[off];
  }
  __builtin_amdgcn_s_waitcnt(0);  // Q frag reads complete before Pu aliases region

  uint* Pu = (uint*)(sm + 16384) + wv * 1024;  // per-wave P, packed hi|lo

  float tsm_v[4];
#pragma unroll
  for (int r = 0; r < 4; ++r)
    tsm_v[r] = tsmask[b * M_ + m0 + wv * 16 + quad * 4 + r];

  float m_i[4] = {-INFINITY, -INFINITY, -INFINITY, -INFINITY};
  float l_i[4] = {0.f, 0.f, 0.f, 0.f};
  f32x4 acc[4];
#pragma unroll
  for (int es = 0; es < 4; ++es) acc[es] = {0.f, 0.f, 0.f, 0.f};

  for (int nc = 0; nc < 16; ++nc) {
    const int n0 = nc * 64;
    __syncthreads();  // prev iter's LDS reads done (iter0: Q frag reads done)
    // ---- stage K rows / V^T rows (wave wv: rows wv*16..+15 of each) ----
#pragma unroll
    for (int i = 0; i < 2; ++i) {
      const int rr = wv * 16 + i * 8;
      const size_t gk = (size_t)(b * N_ + n0 + rr + lrow) * HE + h * 64 + gch8;
      const size_t gv = (size_t)((b * H_ + h) * 64 + rr + lrow) * N_ + n0 + gch8;
      gld16(Kh + gk, &KHT[rr * 64]);
      gld16(Kl + gk, &KLT[rr * 64]);
      gld16(Vth + gv, &VTH[rr * 64]);
      gld16(Vtl + gv, &VTL[rr * 64]);
    }
    __syncthreads();  // drains vmcnt

    // ---- S = Q K^T (split3) ----
    f32x4 s[4];
#pragma unroll
    for (int ns = 0; ns < 4; ++ns) {
      s[ns] = {0.f, 0.f, 0.f, 0.f};
#pragma unroll
      for (int ks = 0; ks < 2; ++ks) {
        const int row = ns * 16 + l15;
        const int off = row * 64 + (((ks * 4 + quad) ^ (row & 7)) << 3);
        const short8 kh = *(const short8*)&KHT[off];
        const short8 kl = *(const short8*)&KLT[off];
        s[ns] = __builtin_amdgcn_mfma_f32_16x16x32_bf16(qh[ks], kh, s[ns], 0, 0, 0);
        s[ns] = __builtin_amdgcn_mfma_f32_16x16x32_bf16(qh[ks], kl, s[ns], 0, 0, 0);
        s[ns] = __builtin_amdgcn_mfma_f32_16x16x32_bf16(ql[ks], kh, s[ns], 0, 0, 0);
      }
    }

    // ---- scale + mask ----
    bool km[4];
#pragma unroll
    for (int ns = 0; ns < 4; ++ns)
      km[ns] = kvmask[b * N_ + n0 + ns * 16 + l15] != 0;
    float sc[4][4];  // [reg r][ns]
#pragma unroll
    for (int ns = 0; ns < 4; ++ns)
#pragma unroll
      for (int r = 0; r < 4; ++r)
        sc[r][ns] = km[ns] ? -INFINITY : s[ns][r] * 0.125f;

    // ---- scores_for_log ----
#pragma unroll
    for (int r = 0; r < 4; ++r) {
      const size_t base =
          ((size_t)(b * H_ + h) * M_ + m0 + wv * 16 + quad * 4 + r) * N_ + n0;
      const bool vr = tsm_v[r] != 0.f;
#pragma unroll
      for (int ns = 0; ns < 4; ++ns)
        scores_out[base + ns * 16 + l15] =
            (vr && !km[ns]) ? sc[r][ns] : NEG_BIG;
    }

    // ---- online softmax + P pack to LDS ----
#pragma unroll
    for (int r = 0; r < 4; ++r) {
      float cm = fmaxf(fmaxf(sc[r][0], sc[r][1]), fmaxf(sc[r][2], sc[r][3]));
#pragma unroll
      for (int o = 1; o < 16; o <<= 1) cm = fmaxf(cm, __shfl_xor(cm, o));
      const float nm = fmaxf(m_i[r], cm);
      const float alpha = (m_i[r] == -INFINITY) ? 0.f : __expf(m_i[r] - nm);
      float ps = 0.f;
      const int pr = quad * 4 + r;
#pragma unroll
      for (int ns = 0; ns < 4; ++ns) {
        const float p = (sc[r][ns] == -INFINITY) ? 0.f : __expf(sc[r][ns] - nm);
        ps += p;
        ushort ph_, pl_;
        bsplit(p, ph_, pl_);
        const int c = ns * 16 + l15;
        Pu[pr * 64 + (((c >> 2) ^ (pr & 7)) << 2) + (c & 3)] = pk(ph_, pl_);
      }
#pragma unroll
      for (int o = 1; o < 16; o <<= 1) ps += __shfl_xor(ps, o);
      l_i[r] = l_i[r] * alpha + ps;
      m_i[r] = nm;
#pragma unroll
      for (int es = 0; es < 4; ++es) acc[es][r] *= alpha;
    }

    // ---- PV (split3); P A-frag from packed LDS, V^T B-frag ----
#pragma unroll
    for (int ks = 0; ks < 2; ++ks) {
      const int c0 = ks * 8 + quad * 2;
      const uint* pb = &Pu[l15 * 64];
      const uint4 u0 = *(const uint4*)&pb[(c0 ^ (l15 & 7)) << 2];
      const uint4 u1 = *(const uint4*)&pb[((c0 + 1) ^ (l15 & 7)) << 2];
      short8 ph, pl;
      const uint* up0 = (const uint*)&u0;
      const uint* up1 = (const uint*)&u1;
#pragma unroll
      for (int j = 0; j < 4; ++j) {
        ph[j] = (short)(up0[j] & 0xffffu); pl[j] = (short)(up0[j] >> 16);
        ph[4 + j] = (short)(up1[j] & 0xffffu); pl[4 + j] = (short)(up1[j] >> 16);
      }
#pragma unroll
      for (int es = 0; es < 4; ++es) {
        const int row = es * 16 + l15;
        const int off = row * 64 + (((ks * 4 + quad) ^ (row & 7)) << 3);
        const short8 vh = *(const short8*)&VTH[off];
        const short8 vl = *(const short8*)&VTL[off];
        acc[es] = __builtin_amdgcn_mfma_f32_16x16x32_bf16(ph, vh, acc[es], 0, 0, 0);
        acc[es] = __builtin_amdgcn_mfma_f32_16x16x32_bf16(ph, vl, acc[es], 0, 0, 0);
        acc[es] = __builtin_amdgcn_mfma_f32_16x16x32_bf16(pl, vh, acc[es], 0, 0, 0);
      }
    }
  }

  // ---- epilogue: out_v = acc / l ----
#pragma unroll
  for (int r = 0; r < 4; ++r) {
    const float inv = (l_i[r] > 0.f) ? 1.f / l_i[r] : 0.f;
    const int grow = b * M_ + m0 + wv * 16 + quad * 4 + r;
#pragma unroll
    for (int es = 0; es < 4; ++es)
      outv[(size_t)grow * HE + h * 64 + es * 16 + l15] = acc[es][r] * inv;
  }
}

// ---------------------------------------------------------------------------
extern "C" void kernel_launch(void* const* d_in, const int* in_sizes, int n_in,
                              void* d_out, int out_size, void* d_ws,
                              size_t ws_size, hipStream_t stream) {
  const float* ts  = (const float*)d_in[0];
  const float* kv  = (const float*)d_in[1];
  const float* tsm = (const float*)d_in[2];
  const unsigned char* kvm = (const unsigned char*)d_in[3];
  const float* Wq = (const float*)d_in[4];
  const float* bq = (const float*)d_in[5];
  const float* Wk = (const float*)d_in[6];
  const float* bk = (const float*)d_in[7];
  const float* Wv = (const float*)d_in[8];
  const float* bv = (const float*)d_in[9];
  const float* Wo = (const float*)d_in[10];
  const float* bo = (const float*)d_in[11];

  float* out        = (float*)d_out;
  float* scores_out = out + (size_t)B_ * M_ * DLLM;

  char* ws = (char*)d_ws;
  constexpr size_t MB = 1024 * 1024;

  if (ws_size >= 260 * MB) {
    // ---------- pre-split path (A operands staged as bf16 hi/lo) ----------
    ushort* Kvh  = (ushort*)(ws);
    ushort* Kvl  = (ushort*)(ws + 64 * MB);
    float*  Vf   = (float*)(ws + 128 * MB);
    ushort* Khp  = (ushort*)(ws + 160 * MB);
    ushort* Klp  = (ushort*)(ws + 176 * MB);
    ushort* Qhp  = (ushort*)(ws + 192 * MB);
    ushort* Qlp  = (ushort*)(ws + 200 * MB);
    ushort* Tsh  = (ushort*)(ws + 208 * MB);
    ushort* Tsl  = (ushort*)(ws + 216 * MB);
    ushort* Wqh  = (ushort*)(ws + 224 * MB);
    ushort* Wql  = (ushort*)(ws + 226 * MB);
    ushort* Wkh  = (ushort*)(ws + 228 * MB);
    ushort* Wkl  = (ushort*)(ws + 236 * MB);
    ushort* Wvh  = (ushort*)(ws + 244 * MB);
    ushort* Wvl  = (ushort*)(ws + 252 * MB);
    // aliases valid once predecessors are dead (stream-ordered)
    ushort* Vthp  = (ushort*)(ws);
    ushort* Vtlp  = (ushort*)(ws + 16 * MB);
    ushort* outvh = (ushort*)(ws + 32 * MB);
    ushort* outvl = (ushort*)(ws + 40 * MB);
    ushort* Woh   = (ushort*)(ws + 64 * MB);
    ushort* Wol   = (ushort*)(ws + 72 * MB);
    float*  outv  = (float*)(ws + 128 * MB);

    // input pre-splits
    {
      const int n8_ts = (B_ * M_ * DTS) / 8;     // 512K
      asplit_kernel<<<dim3(n8_ts / 256), 256, 0, stream>>>(ts, Tsh, Tsl, n8_ts);
      const int n8_kv = (B_ * N_ * DLLM) / 8;    // 4M
      asplit_kernel<<<dim3(n8_kv / 256), 256, 0, stream>>>(kv, Kvh, Kvl, n8_kv);
    }

    // weight transpose+split
    tsplit_kernel<<<dim3(HE / 32, DTS / 32), 256, 0, stream>>>(Wq, Wqh, Wql, DTS, HE);
    tsplit_kernel<<<dim3(HE / 32, DLLM / 32), 256, 0, stream>>>(Wk, Wkh, Wkl, DLLM, HE);
    tsplit_kernel<<<dim3(HE / 32, DLLM / 32), 256, 0, stream>>>(Wv, Wvh, Wvl, DLLM, HE);

    // projections (both operands pre-split)
    gemm_bb_kernel<false, true><<<dim3(HE / 128, (B_ * M_) / 128), 256, 0, stream>>>(
        Tsh, Tsl, Wqh, Wql, bq, nullptr, nullptr, Qhp, Qlp, DTS, HE);
    gemm_bb_kernel<false, true><<<dim3(HE / 128, (B_ * N_) / 128), 256, 0, stream>>>(
        Kvh, Kvl, Wkh, Wkl, bk, nullptr, nullptr, Khp, Klp, DLLM, HE);
    gemm_bb_kernel<false, false><<<dim3(HE / 128, (B_ * N_) / 128), 256, 0, stream>>>(
        Kvh, Kvl, Wvh, Wvl, bv, nullptr, Vf, nullptr, nullptr, DLLM, HE);

    // V^T split prep (Kv regions dead now; writes into [0,32))
    vtprep_kernel<<<dim3(B_ * H_ * 16), 256, 0, stream>>>(Vf, Vthp, Vtlp);

    // MFMA flash attention (+ scores_for_log); writes outv fp32 over dead Vf
    attn_mfma_kernel<<<dim3(B_ * H_ * (M_ / 64)), 256, 0, stream>>>(
        Qhp, Qlp, Khp, Klp, Vthp, Vtlp, kvm, tsm, outv, scores_out);

    // split attn output for pre-split O-GEMM
    {
      const int n8_o = (B_ * M_ * HE) / 8;       // 512K
      asplit_kernel<<<dim3(n8_o / 256), 256, 0, stream>>>(outv, outvh, outvl, n8_o);
    }

    // output projection
    tsplit_kernel<<<dim3(DLLM / 32, HE / 32), 256, 0, stream>>>(Wo, Woh, Wol, HE, DLLM);
    gemm_bb_kernel<true, false><<<dim3(DLLM / 128, (B_ * M_) / 128), 256, 0, stream>>>(
        outvh, outvl, Woh, Wol, bo, tsm, out, nullptr, nullptr, HE, DLLM);
  } else {
    // ---------- fallback: exact verified baseline path (116 MB) ----------
    float*  Vf   = (float*)(ws);
    float*  outv = (float*)(ws);
    ushort* Qhp  = (ushort*)(ws + 32 * MB);
    ushort* Qlp  = (ushort*)(ws + 40 * MB);
    ushort* Khp  = (ushort*)(ws + 48 * MB);
    ushort* Klp  = (ushort*)(ws + 64 * MB);
    ushort* Wqh  = (ushort*)(ws + 80 * MB);
    ushort* Wql  = (ushort*)(ws + 82 * MB);
    ushort* Wkh  = (ushort*)(ws + 84 * MB);
    ushort* Wkl  = (ushort*)(ws + 92 * MB);
    ushort* Wvh  = (ushort*)(ws + 100 * MB);
    ushort* Wvl  = (ushort*)(ws + 108 * MB);
    ushort* Vthp = (ushort*)(ws + 84 * MB);
    ushort* Vtlp = (ushort*)(ws + 100 * MB);
    ushort* Woh  = (ushort*)(ws + 48 * MB);
    ushort* Wol  = (ushort*)(ws + 56 * MB);

    tsplit_kernel<<<dim3(HE / 32, DTS / 32), 256, 0, stream>>>(Wq, Wqh, Wql, DTS, HE);
    tsplit_kernel<<<dim3(HE / 32, DLLM / 32), 256, 0, stream>>>(Wk, Wkh, Wkl, DLLM, HE);
    tsplit_kernel<<<dim3(HE / 32, DLLM / 32), 256, 0, stream>>>(Wv, Wvh, Wvl, DLLM, HE);

    gemm_split3_kernel<false, true><<<dim3(HE / 128, (B_ * M_) / 128), 256, 0, stream>>>(
        ts, Wqh, Wql, bq, nullptr, nullptr, Qhp, Qlp, DTS, HE);
    gemm_split3_kernel<false, true><<<dim3(HE / 128, (B_ * N_) / 128), 256, 0, stream>>>(
        kv, Wkh, Wkl, bk, nullptr, nullptr, Khp, Klp, DLLM, HE);
    gemm_split3_kernel<false, false><<<dim3(HE / 128, (B_ * N_) / 128), 256, 0, stream>>>(
        kv, Wvh, Wvl, bv, nullptr, Vf, nullptr, nullptr, DLLM, HE);

    vtprep_kernel<<<dim3(B_ * H_ * 16), 256, 0, stream>>>(Vf, Vthp, Vtlp);

    attn_mfma_kernel<<<dim3(B_ * H_ * (M_ / 64)), 256, 0, stream>>>(
        Qhp, Qlp, Khp, Klp, Vthp, Vtlp, kvm, tsm, outv, scores_out);

    tsplit_kernel<<<dim3(DLLM / 32, HE / 32), 256, 0, stream>>>(Wo, Woh, Wol, HE, DLLM);
    gemm_split3_kernel<true, false><<<dim3(DLLM / 128, (B_ * M_) / 128), 256, 0, stream>>>(
        outv, Woh, Wol, bo, tsm, out, nullptr, nullptr, HE, DLLM);
  }
}

// Round 4
// 1245.214 us; speedup vs baseline: 1.0702x; 1.0702x over previous
//
#include <hip/hip_runtime.h>
#include <math.h>

// Problem constants (match reference)
namespace {
constexpr int B_   = 8;
constexpr int M_   = 512;
constexpr int N_   = 1024;
constexpr int DTS  = 1024;
constexpr int DLLM = 4096;
constexpr int H_   = 16;
constexpr int E_   = 64;
constexpr int HE   = H_ * E_;   // 1024
// Finite stand-in for -inf in scores_for_log.
constexpr float NEG_BIG = -3.0e38f;
}

typedef __attribute__((ext_vector_type(4))) float f32x4;
typedef __attribute__((ext_vector_type(8))) short short8;
typedef unsigned int uint;
typedef unsigned short ushort;

// RNE split x = hi + lo (both representable as bf16; lo truncated).
__device__ inline void bsplit(float x, ushort& h, ushort& l) {
  uint u = __float_as_uint(x);
  uint hr = (u + 0x7FFFu + ((u >> 16) & 1u)) & 0xFFFF0000u;
  float lof = x - __uint_as_float(hr);
  h = (ushort)(hr >> 16);
  l = (ushort)(__float_as_uint(lof) >> 16);
}
__device__ inline uint pk(ushort a, ushort b) { return (uint)a | ((uint)b << 16); }

// async 16B global->LDS (m97-verified path)
__device__ inline void gld16(const void* g, void* l) {
  __builtin_amdgcn_global_load_lds(
      (const __attribute__((address_space(1))) uint*)g,
      (__attribute__((address_space(3))) uint*)l, 16, 0, 0);
}

// ---------------------------------------------------------------------------
// One-shot elementwise fp32 -> bf16 hi/lo split (row-major, no transpose).
// ---------------------------------------------------------------------------
__global__ __launch_bounds__(256) void asplit_kernel(
    const float* __restrict__ X, ushort* __restrict__ Xh,
    ushort* __restrict__ Xl, int n8) {
  const int idx = blockIdx.x * 256 + threadIdx.x;
  if (idx >= n8) return;
  const float4 a = *(const float4*)(X + (size_t)idx * 8);
  const float4 b = *(const float4*)(X + (size_t)idx * 8 + 4);
  float f[8] = {a.x, a.y, a.z, a.w, b.x, b.y, b.z, b.w};
  short8 h, l;
#pragma unroll
  for (int j = 0; j < 8; ++j) {
    ushort hh, ll;
    bsplit(f[j], hh, ll);
    h[j] = (short)hh;
    l[j] = (short)ll;
  }
  *(short8*)(Xh + (size_t)idx * 8) = h;
  *(short8*)(Xl + (size_t)idx * 8) = l;
}

// ---------------------------------------------------------------------------
// Weight transpose + bf16 split: W fp32 [K][N] -> Wth, Wtl bf16 [N][K].
// ---------------------------------------------------------------------------
__global__ __launch_bounds__(256) void tsplit_kernel(
    const float* __restrict__ W, ushort* __restrict__ Wth,
    ushort* __restrict__ Wtl, int K, int Nc) {
  __shared__ float S[32][33];
  const int t = threadIdx.x;
  const int n0 = blockIdx.x * 32, k0 = blockIdx.y * 32;
  const int c = t & 31, r8 = t >> 5;
#pragma unroll
  for (int i = 0; i < 4; ++i) {
    const int rr = r8 + i * 8;
    S[rr][c] = W[(size_t)(k0 + rr) * Nc + n0 + c];
  }
  __syncthreads();
#pragma unroll
  for (int i = 0; i < 4; ++i) {
    const int nn = r8 + i * 8;
    const float x = S[c][nn];
    ushort h, l;
    bsplit(x, h, l);
    const size_t o = (size_t)(n0 + nn) * K + k0 + c;
    Wth[o] = h;
    Wtl[o] = l;
  }
}

// ---------------------------------------------------------------------------
// V transpose prep: V fp32 [b*n][HE] -> Vth/Vtl bf16 [(b*H+h)*64+e][N].
// ---------------------------------------------------------------------------
__global__ __launch_bounds__(256) void vtprep_kernel(
    const float* __restrict__ V, ushort* __restrict__ Vth,
    ushort* __restrict__ Vtl) {
  __shared__ float S[64][68];
  const int t  = threadIdx.x;
  const int nt = blockIdx.x & 15;
  const int h  = (blockIdx.x >> 4) & 15;
  const int b  = blockIdx.x >> 8;
  const int n0 = nt * 64;
#pragma unroll
  for (int i = 0; i < 4; ++i) {
    const int idx = i * 256 + t;
    const int row = idx >> 4, c4 = (idx & 15) * 4;
    *(float4*)&S[row][c4] =
        *(const float4*)&V[(size_t)(b * N_ + n0 + row) * HE + h * 64 + c4];
  }
  __syncthreads();
  const int e = t >> 2, nch = (t & 3) * 16;
  short8 h0, h1, l0, l1;
#pragma unroll
  for (int j = 0; j < 8; ++j) {
    ushort hh, ll;
    bsplit(S[nch + j][e], hh, ll);
    h0[j] = (short)hh; l0[j] = (short)ll;
    bsplit(S[nch + 8 + j][e], hh, ll);
    h1[j] = (short)hh; l1[j] = (short)ll;
  }
  const size_t off = (size_t)((b * H_ + h) * 64 + e) * N_ + n0 + nch;
  *(short8*)(Vth + off)     = h0;
  *(short8*)(Vth + off + 8) = h1;
  *(short8*)(Vtl + off)     = l0;
  *(short8*)(Vtl + off + 8) = l1;
}

// ---------------------------------------------------------------------------
// bf16x3 split MFMA GEMM, fp32 A converted in-loop (verified fallback path).
// ---------------------------------------------------------------------------
template <bool ROWMASK, bool SPLITOUT>
__global__ __launch_bounds__(256) void gemm_split3_kernel(
    const float* __restrict__ A, const ushort* __restrict__ Bth,
    const ushort* __restrict__ Btl, const float* __restrict__ bias,
    const float* __restrict__ rowmask, float* __restrict__ C,
    ushort* __restrict__ Ch, ushort* __restrict__ Cl, int Kd, int Nc) {
  __shared__ ushort Ah[128][32];
  __shared__ ushort Al[128][32];
  __shared__ ushort Bh[128][32];
  __shared__ ushort Bl[128][32];

  const int t    = threadIdx.x;
  const int lane = t & 63;
  const int wv   = t >> 6;
  const int l15  = lane & 15;
  const int quad = lane >> 4;
  const int wm   = (wv & 1) * 64;
  const int wn   = (wv >> 1) * 64;
  const int row0 = blockIdx.y * 128;
  const int col0 = blockIdx.x * 128;

  const int arow = t >> 1;
  const int half = t & 1;
  const float* Ap = A + (size_t)(row0 + arow) * Kd + half * 16;

  const int bn  = (lane >> 2);
  const int bk8 = (lane & 3) * 8;
  const ushort* Bhp = Bth + (size_t)(col0 + wv * 32 + bn) * Kd + bk8;
  const ushort* Blp = Btl + (size_t)(col0 + wv * 32 + bn) * Kd + bk8;

  f32x4 acc[4][4];
#pragma unroll
  for (int i = 0; i < 4; ++i)
#pragma unroll
    for (int j = 0; j < 4; ++j) acc[i][j] = {0.f, 0.f, 0.f, 0.f};

  for (int k0 = 0; k0 < Kd; k0 += 32) {
    __syncthreads();
#pragma unroll
    for (int j = 0; j < 2; ++j) {
      const int n = wv * 32 + j * 16 + bn;
      gld16(Bhp + (size_t)j * 16 * Kd + k0, &Bh[n][bk8]);
      gld16(Blp + (size_t)j * 16 * Kd + k0, &Bl[n][bk8]);
    }
    float f[16];
#pragma unroll
    for (int i = 0; i < 4; ++i) {
      const float4 v = *(const float4*)(Ap + k0 + i * 4);
      f[i * 4 + 0] = v.x; f[i * 4 + 1] = v.y;
      f[i * 4 + 2] = v.z; f[i * 4 + 3] = v.w;
    }
    ushort hh[16], ll[16];
#pragma unroll
    for (int i = 0; i < 16; ++i) bsplit(f[i], hh[i], ll[i]);
    uint4 wh0 = {pk(hh[0], hh[1]), pk(hh[2], hh[3]), pk(hh[4], hh[5]), pk(hh[6], hh[7])};
    uint4 wh1 = {pk(hh[8], hh[9]), pk(hh[10], hh[11]), pk(hh[12], hh[13]), pk(hh[14], hh[15])};
    uint4 wl0 = {pk(ll[0], ll[1]), pk(ll[2], ll[3]), pk(ll[4], ll[5]), pk(ll[6], ll[7])};
    uint4 wl1 = {pk(ll[8], ll[9]), pk(ll[10], ll[11]), pk(ll[12], ll[13]), pk(ll[14], ll[15])};
    *(uint4*)&Ah[arow][half * 16 + 0] = wh0;
    *(uint4*)&Ah[arow][half * 16 + 8] = wh1;
    *(uint4*)&Al[arow][half * 16 + 0] = wl0;
    *(uint4*)&Al[arow][half * 16 + 8] = wl1;

    __syncthreads();

    short8 ah[4], al[4], bh[4], bl[4];
#pragma unroll
    for (int mi = 0; mi < 4; ++mi) {
      ah[mi] = *(const short8*)&Ah[wm + mi * 16 + l15][quad * 8];
      al[mi] = *(const short8*)&Al[wm + mi * 16 + l15][quad * 8];
    }
#pragma unroll
    for (int ni = 0; ni < 4; ++ni) {
      bh[ni] = *(const short8*)&Bh[wn + ni * 16 + l15][quad * 8];
      bl[ni] = *(const short8*)&Bl[wn + ni * 16 + l15][quad * 8];
    }
#pragma unroll
    for (int mi = 0; mi < 4; ++mi)
#pragma unroll
      for (int ni = 0; ni < 4; ++ni) {
        acc[mi][ni] = __builtin_amdgcn_mfma_f32_16x16x32_bf16(
            ah[mi], bh[ni], acc[mi][ni], 0, 0, 0);
        acc[mi][ni] = __builtin_amdgcn_mfma_f32_16x16x32_bf16(
            ah[mi], bl[ni], acc[mi][ni], 0, 0, 0);
        acc[mi][ni] = __builtin_amdgcn_mfma_f32_16x16x32_bf16(
            al[mi], bh[ni], acc[mi][ni], 0, 0, 0);
      }
  }

  float bb[4];
#pragma unroll
  for (int ni = 0; ni < 4; ++ni) bb[ni] = bias[col0 + wn + ni * 16 + l15];
#pragma unroll
  for (int mi = 0; mi < 4; ++mi)
#pragma unroll
    for (int r = 0; r < 4; ++r) {
      const int row = row0 + wm + mi * 16 + quad * 4 + r;
      const float rm = ROWMASK ? rowmask[row] : 1.f;
#pragma unroll
      for (int ni = 0; ni < 4; ++ni) {
        const int col = col0 + wn + ni * 16 + l15;
        float v = acc[mi][ni][r] + bb[ni];
        if (SPLITOUT) {
          ushort vh, vl;
          bsplit(v, vh, vl);
          Ch[(size_t)row * Nc + col] = vh;
          Cl[(size_t)row * Nc + col] = vl;
        } else {
          if (ROWMASK) v *= rm;
          C[(size_t)row * Nc + col] = v;
        }
      }
    }
}

// ---------------------------------------------------------------------------
// bf16x3 split MFMA GEMM, BOTH operands pre-split bf16 hi/lo (R2 body).
// R4 change: 1D grid + XCD-aware remap. Dispatch round-robins lin%8 across
// XCDs; we map lin -> (xb,yb) with lin%8 == yb%8 so ALL col-blocks sharing an
// A-panel land on the SAME XCD (A-panel slice reused from that XCD's L2
// instead of re-fetched 8x over the fabric; R3 counters: FETCH 944MB vs
// 144MB unique = 8x A duplication). Requires GY % 8 == 0 (holds: 32/64).
// ---------------------------------------------------------------------------
template <bool ROWMASK, bool SPLITOUT>
__global__ __launch_bounds__(256) void gemm_bb_kernel(
    const ushort* __restrict__ Ath, const ushort* __restrict__ Atl,
    const ushort* __restrict__ Bth, const ushort* __restrict__ Btl,
    const float* __restrict__ bias, const float* __restrict__ rowmask,
    float* __restrict__ C, ushort* __restrict__ Ch, ushort* __restrict__ Cl,
    int Kd, int Nc, int gx) {
  __shared__ ushort Ah[128][32];
  __shared__ ushort Al[128][32];
  __shared__ ushort Bh[128][32];
  __shared__ ushort Bl[128][32];

  const int t    = threadIdx.x;
  const int lane = t & 63;
  const int wv   = t >> 6;
  const int l15  = lane & 15;
  const int quad = lane >> 4;
  const int wm   = (wv & 1) * 64;
  const int wn   = (wv >> 1) * 64;

  // XCD-aware decode: lin = (yb%8) + 8*xb + 8*gx*(yb/8)  (bijective)
  const int lin  = blockIdx.x;
  const int xb   = (lin >> 3) % gx;
  const int yb   = (lin & 7) + 8 * ((lin >> 3) / gx);
  const int row0 = yb * 128;
  const int col0 = xb * 128;

  // per-lane source for 16B async staging (lane l -> LDS base + l*16B)
  const int rn  = (lane >> 2);
  const int rk8 = (lane & 3) * 8;
  const ushort* Ahp = Ath + (size_t)(row0 + wv * 32 + rn) * Kd + rk8;
  const ushort* Alp = Atl + (size_t)(row0 + wv * 32 + rn) * Kd + rk8;
  const ushort* Bhp = Bth + (size_t)(col0 + wv * 32 + rn) * Kd + rk8;
  const ushort* Blp = Btl + (size_t)(col0 + wv * 32 + rn) * Kd + rk8;

  f32x4 acc[4][4];
#pragma unroll
  for (int i = 0; i < 4; ++i)
#pragma unroll
    for (int j = 0; j < 4; ++j) acc[i][j] = {0.f, 0.f, 0.f, 0.f};

  for (int k0 = 0; k0 < Kd; k0 += 32) {
    __syncthreads();
#pragma unroll
    for (int j = 0; j < 2; ++j) {
      const int rr = wv * 32 + j * 16;
      const size_t o = (size_t)j * 16 * Kd + k0;
      gld16(Ahp + o, &Ah[rr][0]);
      gld16(Alp + o, &Al[rr][0]);
      gld16(Bhp + o, &Bh[rr][0]);
      gld16(Blp + o, &Bl[rr][0]);
    }
    __syncthreads();  // drains vmcnt -> staged tiles visible

    short8 ah[4], al[4], bh[4], bl[4];
#pragma unroll
    for (int mi = 0; mi < 4; ++mi) {
      ah[mi] = *(const short8*)&Ah[wm + mi * 16 + l15][quad * 8];
      al[mi] = *(const short8*)&Al[wm + mi * 16 + l15][quad * 8];
    }
#pragma unroll
    for (int ni = 0; ni < 4; ++ni) {
      bh[ni] = *(const short8*)&Bh[wn + ni * 16 + l15][quad * 8];
      bl[ni] = *(const short8*)&Bl[wn + ni * 16 + l15][quad * 8];
    }
#pragma unroll
    for (int mi = 0; mi < 4; ++mi)
#pragma unroll
      for (int ni = 0; ni < 4; ++ni) {
        acc[mi][ni] = __builtin_amdgcn_mfma_f32_16x16x32_bf16(
            ah[mi], bh[ni], acc[mi][ni], 0, 0, 0);
        acc[mi][ni] = __builtin_amdgcn_mfma_f32_16x16x32_bf16(
            ah[mi], bl[ni], acc[mi][ni], 0, 0, 0);
        acc[mi][ni] = __builtin_amdgcn_mfma_f32_16x16x32_bf16(
            al[mi], bh[ni], acc[mi][ni], 0, 0, 0);
      }
  }

  float bb[4];
#pragma unroll
  for (int ni = 0; ni < 4; ++ni) bb[ni] = bias[col0 + wn + ni * 16 + l15];
#pragma unroll
  for (int mi = 0; mi < 4; ++mi)
#pragma unroll
    for (int r = 0; r < 4; ++r) {
      const int row = row0 + wm + mi * 16 + quad * 4 + r;
      const float rm = ROWMASK ? rowmask[row] : 1.f;
#pragma unroll
      for (int ni = 0; ni < 4; ++ni) {
        const int col = col0 + wn + ni * 16 + l15;
        float v = acc[mi][ni][r] + bb[ni];
        if (SPLITOUT) {
          ushort vh, vl;
          bsplit(v, vh, vl);
          Ch[(size_t)row * Nc + col] = vh;
          Cl[(size_t)row * Nc + col] = vl;
        } else {
          if (ROWMASK) v *= rm;
          C[(size_t)row * Nc + col] = v;
        }
      }
    }
}

// ---------------------------------------------------------------------------
// MFMA flash attention. Block = (b, h, 64 q-rows); 4 waves x 16 rows.
// ---------------------------------------------------------------------------
__global__ __launch_bounds__(256) void attn_mfma_kernel(
    const ushort* __restrict__ Qh, const ushort* __restrict__ Ql,
    const ushort* __restrict__ Kh, const ushort* __restrict__ Kl,
    const ushort* __restrict__ Vth, const ushort* __restrict__ Vtl,
    const unsigned char* __restrict__ kvmask, const float* __restrict__ tsmask,
    float* __restrict__ outv, float* __restrict__ scores_out) {
  __shared__ __align__(16) ushort sm[24576];  // 48 KB
  ushort* KHT = sm;            // [64 rows(n)][64 e] swizzled
  ushort* KLT = sm + 4096;
  ushort* VTH = sm + 8192;     // [64 rows(e)][64 n] swizzled
  ushort* VTL = sm + 12288;
  ushort* QHT = sm + 16384;    // [64 rows(m)][64 e] swizzled (dead after frag read)
  ushort* QLT = sm + 20480;

  const int t = threadIdx.x, lane = t & 63, wv = t >> 6;
  const int l15 = lane & 15, quad = lane >> 4;
  const int blk = blockIdx.x;          // b*128 + h*8 + mt
  const int mt = blk & 7;
  const int h  = (blk >> 3) & 15;
  const int b  = blk >> 7;
  const int m0 = mt * 64;
  const int lrow = lane >> 3, lch = lane & 7;
  const int gch8 = (lch ^ (lrow & 7)) * 8;  // swizzled 16B-chunk, ushort offset

  // ---- stage Q tile (wave wv: rows wv*16..+15), hi and lo ----
#pragma unroll
  for (int i = 0; i < 2; ++i) {
    const int rr = wv * 16 + i * 8;   // wave-uniform LDS row base
    const size_t g = (size_t)(b * M_ + m0 + rr + lrow) * HE + h * 64 + gch8;
    gld16(Qh + g, &QHT[rr * 64]);
    gld16(Ql + g, &QLT[rr * 64]);
  }
  __syncthreads();

  short8 qh[2], ql[2];
#pragma unroll
  for (int ks = 0; ks < 2; ++ks) {
    const int row = wv * 16 + l15;
    const int off = row * 64 + (((ks * 4 + quad) ^ (row & 7)) << 3);
    qh[ks] = *(const short8*)&QHT[off];
    ql[ks] = *(const short8*)&QLT[off];
  }
  __builtin_amdgcn_s_waitcnt(0);  // Q frag reads complete before Pu aliases region

  uint* Pu = (uint*)(sm + 16384) + wv * 1024;  // per-wave P, packed hi|lo

  float tsm_v[4];
#pragma unroll
  for (int r = 0; r < 4; ++r)
    tsm_v[r] = tsmask[b * M_ + m0 + wv * 16 + quad * 4 + r];

  float m_i[4] = {-INFINITY, -INFINITY, -INFINITY, -INFINITY};
  float l_i[4] = {0.f, 0.f, 0.f, 0.f};
  f32x4 acc[4];
#pragma unroll
  for (int es = 0; es < 4; ++es) acc[es] = {0.f, 0.f, 0.f, 0.f};

  for (int nc = 0; nc < 16; ++nc) {
    const int n0 = nc * 64;
    __syncthreads();  // prev iter's LDS reads done (iter0: Q frag reads done)
    // ---- stage K rows / V^T rows (wave wv: rows wv*16..+15 of each) ----
#pragma unroll
    for (int i = 0; i < 2; ++i) {
      const int rr = wv * 16 + i * 8;
      const size_t gk = (size_t)(b * N_ + n0 + rr + lrow) * HE + h * 64 + gch8;
      const size_t gv = (size_t)((b * H_ + h) * 64 + rr + lrow) * N_ + n0 + gch8;
      gld16(Kh + gk, &KHT[rr * 64]);
      gld16(Kl + gk, &KLT[rr * 64]);
      gld16(Vth + gv, &VTH[rr * 64]);
      gld16(Vtl + gv, &VTL[rr * 64]);
    }
    __syncthreads();  // drains vmcnt

    // ---- S = Q K^T (split3) ----
    f32x4 s[4];
#pragma unroll
    for (int ns = 0; ns < 4; ++ns) {
      s[ns] = {0.f, 0.f, 0.f, 0.f};
#pragma unroll
      for (int ks = 0; ks < 2; ++ks) {
        const int row = ns * 16 + l15;
        const int off = row * 64 + (((ks * 4 + quad) ^ (row & 7)) << 3);
        const short8 kh = *(const short8*)&KHT[off];
        const short8 kl = *(const short8*)&KLT[off];
        s[ns] = __builtin_amdgcn_mfma_f32_16x16x32_bf16(qh[ks], kh, s[ns], 0, 0, 0);
        s[ns] = __builtin_amdgcn_mfma_f32_16x16x32_bf16(qh[ks], kl, s[ns], 0, 0, 0);
        s[ns] = __builtin_amdgcn_mfma_f32_16x16x32_bf16(ql[ks], kh, s[ns], 0, 0, 0);
      }
    }

    // ---- scale + mask ----
    bool km[4];
#pragma unroll
    for (int ns = 0; ns < 4; ++ns)
      km[ns] = kvmask[b * N_ + n0 + ns * 16 + l15] != 0;
    float sc[4][4];  // [reg r][ns]
#pragma unroll
    for (int ns = 0; ns < 4; ++ns)
#pragma unroll
      for (int r = 0; r < 4; ++r)
        sc[r][ns] = km[ns] ? -INFINITY : s[ns][r] * 0.125f;

    // ---- scores_for_log ----
#pragma unroll
    for (int r = 0; r < 4; ++r) {
      const size_t base =
          ((size_t)(b * H_ + h) * M_ + m0 + wv * 16 + quad * 4 + r) * N_ + n0;
      const bool vr = tsm_v[r] != 0.f;
#pragma unroll
      for (int ns = 0; ns < 4; ++ns)
        scores_out[base + ns * 16 + l15] =
            (vr && !km[ns]) ? sc[r][ns] : NEG_BIG;
    }

    // ---- online softmax + P pack to LDS ----
#pragma unroll
    for (int r = 0; r < 4; ++r) {
      float cm = fmaxf(fmaxf(sc[r][0], sc[r][1]), fmaxf(sc[r][2], sc[r][3]));
#pragma unroll
      for (int o = 1; o < 16; o <<= 1) cm = fmaxf(cm, __shfl_xor(cm, o));
      const float nm = fmaxf(m_i[r], cm);
      const float alpha = (m_i[r] == -INFINITY) ? 0.f : __expf(m_i[r] - nm);
      float ps = 0.f;
      const int pr = quad * 4 + r;
#pragma unroll
      for (int ns = 0; ns < 4; ++ns) {
        const float p = (sc[r][ns] == -INFINITY) ? 0.f : __expf(sc[r][ns] - nm);
        ps += p;
        ushort ph_, pl_;
        bsplit(p, ph_, pl_);
        const int c = ns * 16 + l15;
        Pu[pr * 64 + (((c >> 2) ^ (pr & 7)) << 2) + (c & 3)] = pk(ph_, pl_);
      }
#pragma unroll
      for (int o = 1; o < 16; o <<= 1) ps += __shfl_xor(ps, o);
      l_i[r] = l_i[r] * alpha + ps;
      m_i[r] = nm;
#pragma unroll
      for (int es = 0; es < 4; ++es) acc[es][r] *= alpha;
    }

    // ---- PV (split3); P A-frag from packed LDS, V^T B-frag ----
#pragma unroll
    for (int ks = 0; ks < 2; ++ks) {
      const int c0 = ks * 8 + quad * 2;
      const uint* pb = &Pu[l15 * 64];
      const uint4 u0 = *(const uint4*)&pb[(c0 ^ (l15 & 7)) << 2];
      const uint4 u1 = *(const uint4*)&pb[((c0 + 1) ^ (l15 & 7)) << 2];
      short8 ph, pl;
      const uint* up0 = (const uint*)&u0;
      const uint* up1 = (const uint*)&u1;
#pragma unroll
      for (int j = 0; j < 4; ++j) {
        ph[j] = (short)(up0[j] & 0xffffu); pl[j] = (short)(up0[j] >> 16);
        ph[4 + j] = (short)(up1[j] & 0xffffu); pl[4 + j] = (short)(up1[j] >> 16);
      }
#pragma unroll
      for (int es = 0; es < 4; ++es) {
        const int row = es * 16 + l15;
        const int off = row * 64 + (((ks * 4 + quad) ^ (row & 7)) << 3);
        const short8 vh = *(const short8*)&VTH[off];
        const short8 vl = *(const short8*)&VTL[off];
        acc[es] = __builtin_amdgcn_mfma_f32_16x16x32_bf16(ph, vh, acc[es], 0, 0, 0);
        acc[es] = __builtin_amdgcn_mfma_f32_16x16x32_bf16(ph, vl, acc[es], 0, 0, 0);
        acc[es] = __builtin_amdgcn_mfma_f32_16x16x32_bf16(pl, vh, acc[es], 0, 0, 0);
      }
    }
  }

  // ---- epilogue: out_v = acc / l ----
#pragma unroll
  for (int r = 0; r < 4; ++r) {
    const float inv = (l_i[r] > 0.f) ? 1.f / l_i[r] : 0.f;
    const int grow = b * M_ + m0 + wv * 16 + quad * 4 + r;
#pragma unroll
    for (int es = 0; es < 4; ++es)
      outv[(size_t)grow * HE + h * 64 + es * 16 + l15] = acc[es][r] * inv;
  }
}

// ---------------------------------------------------------------------------
extern "C" void kernel_launch(void* const* d_in, const int* in_sizes, int n_in,
                              void* d_out, int out_size, void* d_ws,
                              size_t ws_size, hipStream_t stream) {
  const float* ts  = (const float*)d_in[0];
  const float* kv  = (const float*)d_in[1];
  const float* tsm = (const float*)d_in[2];
  const unsigned char* kvm = (const unsigned char*)d_in[3];
  const float* Wq = (const float*)d_in[4];
  const float* bq = (const float*)d_in[5];
  const float* Wk = (const float*)d_in[6];
  const float* bk = (const float*)d_in[7];
  const float* Wv = (const float*)d_in[8];
  const float* bv = (const float*)d_in[9];
  const float* Wo = (const float*)d_in[10];
  const float* bo = (const float*)d_in[11];

  float* out        = (float*)d_out;
  float* scores_out = out + (size_t)B_ * M_ * DLLM;

  char* ws = (char*)d_ws;
  constexpr size_t MB = 1024 * 1024;

  if (ws_size >= 260 * MB) {
    // ---------- pre-split path (A operands staged as bf16 hi/lo) ----------
    ushort* Kvh  = (ushort*)(ws);
    ushort* Kvl  = (ushort*)(ws + 64 * MB);
    float*  Vf   = (float*)(ws + 128 * MB);
    ushort* Khp  = (ushort*)(ws + 160 * MB);
    ushort* Klp  = (ushort*)(ws + 176 * MB);
    ushort* Qhp  = (ushort*)(ws + 192 * MB);
    ushort* Qlp  = (ushort*)(ws + 200 * MB);
    ushort* Tsh  = (ushort*)(ws + 208 * MB);
    ushort* Tsl  = (ushort*)(ws + 216 * MB);
    ushort* Wqh  = (ushort*)(ws + 224 * MB);
    ushort* Wql  = (ushort*)(ws + 226 * MB);
    ushort* Wkh  = (ushort*)(ws + 228 * MB);
    ushort* Wkl  = (ushort*)(ws + 236 * MB);
    ushort* Wvh  = (ushort*)(ws + 244 * MB);
    ushort* Wvl  = (ushort*)(ws + 252 * MB);
    // aliases valid once predecessors are dead (stream-ordered)
    ushort* Vthp  = (ushort*)(ws);
    ushort* Vtlp  = (ushort*)(ws + 16 * MB);
    ushort* outvh = (ushort*)(ws + 32 * MB);
    ushort* outvl = (ushort*)(ws + 40 * MB);
    ushort* Woh   = (ushort*)(ws + 64 * MB);
    ushort* Wol   = (ushort*)(ws + 72 * MB);
    float*  outv  = (float*)(ws + 128 * MB);

    // input pre-splits
    {
      const int n8_ts = (B_ * M_ * DTS) / 8;     // 512K
      asplit_kernel<<<dim3(n8_ts / 256), 256, 0, stream>>>(ts, Tsh, Tsl, n8_ts);
      const int n8_kv = (B_ * N_ * DLLM) / 8;    // 4M
      asplit_kernel<<<dim3(n8_kv / 256), 256, 0, stream>>>(kv, Kvh, Kvl, n8_kv);
    }

    // weight transpose+split
    tsplit_kernel<<<dim3(HE / 32, DTS / 32), 256, 0, stream>>>(Wq, Wqh, Wql, DTS, HE);
    tsplit_kernel<<<dim3(HE / 32, DLLM / 32), 256, 0, stream>>>(Wk, Wkh, Wkl, DLLM, HE);
    tsplit_kernel<<<dim3(HE / 32, DLLM / 32), 256, 0, stream>>>(Wv, Wvh, Wvl, DLLM, HE);

    // projections (both operands pre-split); 1D grid, XCD-aware decode
    gemm_bb_kernel<false, true><<<dim3((HE / 128) * ((B_ * M_) / 128)), 256, 0, stream>>>(
        Tsh, Tsl, Wqh, Wql, bq, nullptr, nullptr, Qhp, Qlp, DTS, HE, HE / 128);
    gemm_bb_kernel<false, true><<<dim3((HE / 128) * ((B_ * N_) / 128)), 256, 0, stream>>>(
        Kvh, Kvl, Wkh, Wkl, bk, nullptr, nullptr, Khp, Klp, DLLM, HE, HE / 128);
    gemm_bb_kernel<false, false><<<dim3((HE / 128) * ((B_ * N_) / 128)), 256, 0, stream>>>(
        Kvh, Kvl, Wvh, Wvl, bv, nullptr, Vf, nullptr, nullptr, DLLM, HE, HE / 128);

    // V^T split prep (Kv regions dead now; writes into [0,32))
    vtprep_kernel<<<dim3(B_ * H_ * 16), 256, 0, stream>>>(Vf, Vthp, Vtlp);

    // MFMA flash attention (+ scores_for_log); writes outv fp32 over dead Vf
    attn_mfma_kernel<<<dim3(B_ * H_ * (M_ / 64)), 256, 0, stream>>>(
        Qhp, Qlp, Khp, Klp, Vthp, Vtlp, kvm, tsm, outv, scores_out);

    // split attn output for pre-split O-GEMM
    {
      const int n8_o = (B_ * M_ * HE) / 8;       // 512K
      asplit_kernel<<<dim3(n8_o / 256), 256, 0, stream>>>(outv, outvh, outvl, n8_o);
    }

    // output projection
    tsplit_kernel<<<dim3(DLLM / 32, HE / 32), 256, 0, stream>>>(Wo, Woh, Wol, HE, DLLM);
    gemm_bb_kernel<true, false><<<dim3((DLLM / 128) * ((B_ * M_) / 128)), 256, 0, stream>>>(
        outvh, outvl, Woh, Wol, bo, tsm, out, nullptr, nullptr, HE, DLLM, DLLM / 128);
  } else {
    // ---------- fallback: exact verified baseline path (116 MB) ----------
    float*  Vf   = (float*)(ws);
    float*  outv = (float*)(ws);
    ushort* Qhp  = (ushort*)(ws + 32 * MB);
    ushort* Qlp  = (ushort*)(ws + 40 * MB);
    ushort* Khp  = (ushort*)(ws + 48 * MB);
    ushort* Klp  = (ushort*)(ws + 64 * MB);
    ushort* Wqh  = (ushort*)(ws + 80 * MB);
    ushort* Wql  = (ushort*)(ws + 82 * MB);
    ushort* Wkh  = (ushort*)(ws + 84 * MB);
    ushort* Wkl  = (ushort*)(ws + 92 * MB);
    ushort* Wvh  = (ushort*)(ws + 100 * MB);
    ushort* Wvl  = (ushort*)(ws + 108 * MB);
    ushort* Vthp = (ushort*)(ws + 84 * MB);
    ushort* Vtlp = (ushort*)(ws + 100 * MB);
    ushort* Woh  = (ushort*)(ws + 48 * MB);
    ushort* Wol  = (ushort*)(ws + 56 * MB);

    tsplit_kernel<<<dim3(HE / 32, DTS / 32), 256, 0, stream>>>(Wq, Wqh, Wql, DTS, HE);
    tsplit_kernel<<<dim3(HE / 32, DLLM / 32), 256, 0, stream>>>(Wk, Wkh, Wkl, DLLM, HE);
    tsplit_kernel<<<dim3(HE / 32, DLLM / 32), 256, 0, stream>>>(Wv, Wvh, Wvl, DLLM, HE);

    gemm_split3_kernel<false, true><<<dim3(HE / 128, (B_ * M_) / 128), 256, 0, stream>>>(
        ts, Wqh, Wql, bq, nullptr, nullptr, Qhp, Qlp, DTS, HE);
    gemm_split3_kernel<false, true><<<dim3(HE / 128, (B_ * N_) / 128), 256, 0, stream>>>(
        kv, Wkh, Wkl, bk, nullptr, nullptr, Khp, Klp, DLLM, HE);
    gemm_split3_kernel<false, false><<<dim3(HE / 128, (B_ * N_) / 128), 256, 0, stream>>>(
        kv, Wvh, Wvl, bv, nullptr, Vf, nullptr, nullptr, DLLM, HE);

    vtprep_kernel<<<dim3(B_ * H_ * 16), 256, 0, stream>>>(Vf, Vthp, Vtlp);

    attn_mfma_kernel<<<dim3(B_ * H_ * (M_ / 64)), 256, 0, stream>>>(
        Qhp, Qlp, Khp, Klp, Vthp, Vtlp, kvm, tsm, outv, scores_out);

    tsplit_kernel<<<dim3(DLLM / 32, HE / 32), 256, 0, stream>>>(Wo, Woh, Wol, HE, DLLM);
    gemm_split3_kernel<true, false><<<dim3(DLLM / 128, (B_ * M_) / 128), 256, 0, stream>>>(
        outv, Woh, Wol, bo, tsm, out, nullptr, nullptr, HE, DLLM);
  }
}

// Round 5
// 1238.685 us; speedup vs baseline: 1.0758x; 1.0053x over previous
//
#include <hip/hip_runtime.h>
#include <math.h>

// Problem constants (match reference)
namespace {
constexpr int B_   = 8;
constexpr int M_   = 512;
constexpr int N_   = 1024;
constexpr int DTS  = 1024;
constexpr int DLLM = 4096;
constexpr int H_   = 16;
constexpr int E_   = 64;
constexpr int HE   = H_ * E_;   // 1024
// Finite stand-in for -inf in scores_for_log.
constexpr float NEG_BIG = -3.0e38f;
}

typedef __attribute__((ext_vector_type(4))) float f32x4;
typedef __attribute__((ext_vector_type(8))) short short8;
typedef unsigned int uint;
typedef unsigned short ushort;

// RNE split x = hi + lo (both representable as bf16; lo truncated).
__device__ inline void bsplit(float x, ushort& h, ushort& l) {
  uint u = __float_as_uint(x);
  uint hr = (u + 0x7FFFu + ((u >> 16) & 1u)) & 0xFFFF0000u;
  float lof = x - __uint_as_float(hr);
  h = (ushort)(hr >> 16);
  l = (ushort)(__float_as_uint(lof) >> 16);
}
__device__ inline uint pk(ushort a, ushort b) { return (uint)a | ((uint)b << 16); }

// async 16B global->LDS (m97-verified path)
__device__ inline void gld16(const void* g, void* l) {
  __builtin_amdgcn_global_load_lds(
      (const __attribute__((address_space(1))) uint*)g,
      (__attribute__((address_space(3))) uint*)l, 16, 0, 0);
}

// ---------------------------------------------------------------------------
// One-shot elementwise fp32 -> bf16 hi/lo split (row-major, no transpose).
// ---------------------------------------------------------------------------
__global__ __launch_bounds__(256) void asplit_kernel(
    const float* __restrict__ X, ushort* __restrict__ Xh,
    ushort* __restrict__ Xl, int n8) {
  const int idx = blockIdx.x * 256 + threadIdx.x;
  if (idx >= n8) return;
  const float4 a = *(const float4*)(X + (size_t)idx * 8);
  const float4 b = *(const float4*)(X + (size_t)idx * 8 + 4);
  float f[8] = {a.x, a.y, a.z, a.w, b.x, b.y, b.z, b.w};
  short8 h, l;
#pragma unroll
  for (int j = 0; j < 8; ++j) {
    ushort hh, ll;
    bsplit(f[j], hh, ll);
    h[j] = (short)hh;
    l[j] = (short)ll;
  }
  *(short8*)(Xh + (size_t)idx * 8) = h;
  *(short8*)(Xl + (size_t)idx * 8) = l;
}

// ---------------------------------------------------------------------------
// Weight transpose + bf16 split: W fp32 [K][N] -> Wth, Wtl bf16 [N][K].
// ---------------------------------------------------------------------------
__global__ __launch_bounds__(256) void tsplit_kernel(
    const float* __restrict__ W, ushort* __restrict__ Wth,
    ushort* __restrict__ Wtl, int K, int Nc) {
  __shared__ float S[32][33];
  const int t = threadIdx.x;
  const int n0 = blockIdx.x * 32, k0 = blockIdx.y * 32;
  const int c = t & 31, r8 = t >> 5;
#pragma unroll
  for (int i = 0; i < 4; ++i) {
    const int rr = r8 + i * 8;
    S[rr][c] = W[(size_t)(k0 + rr) * Nc + n0 + c];
  }
  __syncthreads();
#pragma unroll
  for (int i = 0; i < 4; ++i) {
    const int nn = r8 + i * 8;
    const float x = S[c][nn];
    ushort h, l;
    bsplit(x, h, l);
    const size_t o = (size_t)(n0 + nn) * K + k0 + c;
    Wth[o] = h;
    Wtl[o] = l;
  }
}

// ---------------------------------------------------------------------------
// V transpose prep: V fp32 [b*n][HE] -> Vth/Vtl bf16 [(b*H+h)*64+e][N].
// ---------------------------------------------------------------------------
__global__ __launch_bounds__(256) void vtprep_kernel(
    const float* __restrict__ V, ushort* __restrict__ Vth,
    ushort* __restrict__ Vtl) {
  __shared__ float S[64][68];
  const int t  = threadIdx.x;
  const int nt = blockIdx.x & 15;
  const int h  = (blockIdx.x >> 4) & 15;
  const int b  = blockIdx.x >> 8;
  const int n0 = nt * 64;
#pragma unroll
  for (int i = 0; i < 4; ++i) {
    const int idx = i * 256 + t;
    const int row = idx >> 4, c4 = (idx & 15) * 4;
    *(float4*)&S[row][c4] =
        *(const float4*)&V[(size_t)(b * N_ + n0 + row) * HE + h * 64 + c4];
  }
  __syncthreads();
  const int e = t >> 2, nch = (t & 3) * 16;
  short8 h0, h1, l0, l1;
#pragma unroll
  for (int j = 0; j < 8; ++j) {
    ushort hh, ll;
    bsplit(S[nch + j][e], hh, ll);
    h0[j] = (short)hh; l0[j] = (short)ll;
    bsplit(S[nch + 8 + j][e], hh, ll);
    h1[j] = (short)hh; l1[j] = (short)ll;
  }
  const size_t off = (size_t)((b * H_ + h) * 64 + e) * N_ + n0 + nch;
  *(short8*)(Vth + off)     = h0;
  *(short8*)(Vth + off + 8) = h1;
  *(short8*)(Vtl + off)     = l0;
  *(short8*)(Vtl + off + 8) = l1;
}

// ---------------------------------------------------------------------------
// bf16x3 split MFMA GEMM, fp32 A converted in-loop (verified fallback path).
// ---------------------------------------------------------------------------
template <bool ROWMASK, bool SPLITOUT>
__global__ __launch_bounds__(256) void gemm_split3_kernel(
    const float* __restrict__ A, const ushort* __restrict__ Bth,
    const ushort* __restrict__ Btl, const float* __restrict__ bias,
    const float* __restrict__ rowmask, float* __restrict__ C,
    ushort* __restrict__ Ch, ushort* __restrict__ Cl, int Kd, int Nc) {
  __shared__ ushort Ah[128][32];
  __shared__ ushort Al[128][32];
  __shared__ ushort Bh[128][32];
  __shared__ ushort Bl[128][32];

  const int t    = threadIdx.x;
  const int lane = t & 63;
  const int wv   = t >> 6;
  const int l15  = lane & 15;
  const int quad = lane >> 4;
  const int wm   = (wv & 1) * 64;
  const int wn   = (wv >> 1) * 64;
  const int row0 = blockIdx.y * 128;
  const int col0 = blockIdx.x * 128;

  const int arow = t >> 1;
  const int half = t & 1;
  const float* Ap = A + (size_t)(row0 + arow) * Kd + half * 16;

  const int bn  = (lane >> 2);
  const int bk8 = (lane & 3) * 8;
  const ushort* Bhp = Bth + (size_t)(col0 + wv * 32 + bn) * Kd + bk8;
  const ushort* Blp = Btl + (size_t)(col0 + wv * 32 + bn) * Kd + bk8;

  f32x4 acc[4][4];
#pragma unroll
  for (int i = 0; i < 4; ++i)
#pragma unroll
    for (int j = 0; j < 4; ++j) acc[i][j] = {0.f, 0.f, 0.f, 0.f};

  for (int k0 = 0; k0 < Kd; k0 += 32) {
    __syncthreads();
#pragma unroll
    for (int j = 0; j < 2; ++j) {
      const int n = wv * 32 + j * 16 + bn;
      gld16(Bhp + (size_t)j * 16 * Kd + k0, &Bh[n][bk8]);
      gld16(Blp + (size_t)j * 16 * Kd + k0, &Bl[n][bk8]);
    }
    float f[16];
#pragma unroll
    for (int i = 0; i < 4; ++i) {
      const float4 v = *(const float4*)(Ap + k0 + i * 4);
      f[i * 4 + 0] = v.x; f[i * 4 + 1] = v.y;
      f[i * 4 + 2] = v.z; f[i * 4 + 3] = v.w;
    }
    ushort hh[16], ll[16];
#pragma unroll
    for (int i = 0; i < 16; ++i) bsplit(f[i], hh[i], ll[i]);
    uint4 wh0 = {pk(hh[0], hh[1]), pk(hh[2], hh[3]), pk(hh[4], hh[5]), pk(hh[6], hh[7])};
    uint4 wh1 = {pk(hh[8], hh[9]), pk(hh[10], hh[11]), pk(hh[12], hh[13]), pk(hh[14], hh[15])};
    uint4 wl0 = {pk(ll[0], ll[1]), pk(ll[2], ll[3]), pk(ll[4], ll[5]), pk(ll[6], ll[7])};
    uint4 wl1 = {pk(ll[8], ll[9]), pk(ll[10], ll[11]), pk(ll[12], ll[13]), pk(ll[14], ll[15])};
    *(uint4*)&Ah[arow][half * 16 + 0] = wh0;
    *(uint4*)&Ah[arow][half * 16 + 8] = wh1;
    *(uint4*)&Al[arow][half * 16 + 0] = wl0;
    *(uint4*)&Al[arow][half * 16 + 8] = wl1;

    __syncthreads();

    short8 ah[4], al[4], bh[4], bl[4];
#pragma unroll
    for (int mi = 0; mi < 4; ++mi) {
      ah[mi] = *(const short8*)&Ah[wm + mi * 16 + l15][quad * 8];
      al[mi] = *(const short8*)&Al[wm + mi * 16 + l15][quad * 8];
    }
#pragma unroll
    for (int ni = 0; ni < 4; ++ni) {
      bh[ni] = *(const short8*)&Bh[wn + ni * 16 + l15][quad * 8];
      bl[ni] = *(const short8*)&Bl[wn + ni * 16 + l15][quad * 8];
    }
#pragma unroll
    for (int mi = 0; mi < 4; ++mi)
#pragma unroll
      for (int ni = 0; ni < 4; ++ni) {
        acc[mi][ni] = __builtin_amdgcn_mfma_f32_16x16x32_bf16(
            ah[mi], bh[ni], acc[mi][ni], 0, 0, 0);
        acc[mi][ni] = __builtin_amdgcn_mfma_f32_16x16x32_bf16(
            ah[mi], bl[ni], acc[mi][ni], 0, 0, 0);
        acc[mi][ni] = __builtin_amdgcn_mfma_f32_16x16x32_bf16(
            al[mi], bh[ni], acc[mi][ni], 0, 0, 0);
      }
  }

  float bb[4];
#pragma unroll
  for (int ni = 0; ni < 4; ++ni) bb[ni] = bias[col0 + wn + ni * 16 + l15];
#pragma unroll
  for (int mi = 0; mi < 4; ++mi)
#pragma unroll
    for (int r = 0; r < 4; ++r) {
      const int row = row0 + wm + mi * 16 + quad * 4 + r;
      const float rm = ROWMASK ? rowmask[row] : 1.f;
#pragma unroll
      for (int ni = 0; ni < 4; ++ni) {
        const int col = col0 + wn + ni * 16 + l15;
        float v = acc[mi][ni][r] + bb[ni];
        if (SPLITOUT) {
          ushort vh, vl;
          bsplit(v, vh, vl);
          Ch[(size_t)row * Nc + col] = vh;
          Cl[(size_t)row * Nc + col] = vl;
        } else {
          if (ROWMASK) v *= rm;
          C[(size_t)row * Nc + col] = v;
        }
      }
    }
}

// ---------------------------------------------------------------------------
// bf16x3 split MFMA GEMM, BOTH operands pre-split bf16 hi/lo.
// R5: counted-vmcnt double-buffer pipeline (T3/T4 minimum form):
//   loop top: issue next tile's 8 gld16 into buf^1, then s_waitcnt vmcnt(8)
//   (waits only for the PREVIOUS tile -- issued a full iteration ago, ~landed)
//   + raw s_barrier (no implicit drain). Next tile's loads stay in flight
//   across the whole compute phase => depth-2 pipelining. R3's dbuf failed
//   because __syncthreads() drained the just-issued prefetch (depth-1).
// XCD-aware remap kept from R4 (FETCH 944->144 MB verified).
// ---------------------------------------------------------------------------
template <bool ROWMASK, bool SPLITOUT>
__global__ __launch_bounds__(256) void gemm_bb_kernel(
    const ushort* __restrict__ Ath, const ushort* __restrict__ Atl,
    const ushort* __restrict__ Bth, const ushort* __restrict__ Btl,
    const float* __restrict__ bias, const float* __restrict__ rowmask,
    float* __restrict__ C, ushort* __restrict__ Ch, ushort* __restrict__ Cl,
    int Kd, int Nc, int gx) {
  __shared__ ushort Ah[2][128][32];   // 4 arrays x 2 buf x 8KB = 64 KB
  __shared__ ushort Al[2][128][32];
  __shared__ ushort Bh[2][128][32];
  __shared__ ushort Bl[2][128][32];

  const int t    = threadIdx.x;
  const int lane = t & 63;
  const int wv   = t >> 6;
  const int l15  = lane & 15;
  const int quad = lane >> 4;
  const int wm   = (wv & 1) * 64;
  const int wn   = (wv >> 1) * 64;

  // XCD-aware decode: lin = (yb%8) + 8*xb + 8*gx*(yb/8)  (bijective)
  const int lin  = blockIdx.x;
  const int xb   = (lin >> 3) % gx;
  const int yb   = (lin & 7) + 8 * ((lin >> 3) / gx);
  const int row0 = yb * 128;
  const int col0 = xb * 128;

  // per-lane source for 16B async staging (lane l -> LDS base + l*16B)
  const int rn  = (lane >> 2);
  const int rk8 = (lane & 3) * 8;
  const ushort* Ahp = Ath + (size_t)(row0 + wv * 32 + rn) * Kd + rk8;
  const ushort* Alp = Atl + (size_t)(row0 + wv * 32 + rn) * Kd + rk8;
  const ushort* Bhp = Bth + (size_t)(col0 + wv * 32 + rn) * Kd + rk8;
  const ushort* Blp = Btl + (size_t)(col0 + wv * 32 + rn) * Kd + rk8;

  f32x4 acc[4][4];
#pragma unroll
  for (int i = 0; i < 4; ++i)
#pragma unroll
    for (int j = 0; j < 4; ++j) acc[i][j] = {0.f, 0.f, 0.f, 0.f};

  // prologue: stage tile 0 into buffer 0 (8 gld16 per thread)
#pragma unroll
  for (int j = 0; j < 2; ++j) {
    const int rr = wv * 32 + j * 16;
    const size_t o = (size_t)j * 16 * Kd;
    gld16(Ahp + o, &Ah[0][rr][0]);
    gld16(Alp + o, &Al[0][rr][0]);
    gld16(Bhp + o, &Bh[0][rr][0]);
    gld16(Blp + o, &Bl[0][rr][0]);
  }

  int cur = 0;
  for (int k0 = 0; k0 < Kd; k0 += 32) {
    const bool has_next = (k0 + 32 < Kd);
    if (has_next) {
      const int nb = cur ^ 1;
#pragma unroll
      for (int j = 0; j < 2; ++j) {
        const int rr = wv * 32 + j * 16;
        const size_t o = (size_t)j * 16 * Kd + k0 + 32;
        gld16(Ahp + o, &Ah[nb][rr][0]);
        gld16(Alp + o, &Al[nb][rr][0]);
        gld16(Bhp + o, &Bh[nb][rr][0]);
        gld16(Blp + o, &Bl[nb][rr][0]);
      }
      // wait for the PREVIOUS tile's 8 loads only; the 8 just issued stay
      // in flight across both barriers and the whole compute phase.
      asm volatile("s_waitcnt vmcnt(8)" ::: "memory");
    } else {
      asm volatile("s_waitcnt vmcnt(0)" ::: "memory");
    }
    __builtin_amdgcn_sched_barrier(0);
    __builtin_amdgcn_s_barrier();      // raw barrier: no implicit drain
    __builtin_amdgcn_sched_barrier(0);

    short8 ah[4], al[4], bh[4], bl[4];
#pragma unroll
    for (int mi = 0; mi < 4; ++mi) {
      ah[mi] = *(const short8*)&Ah[cur][wm + mi * 16 + l15][quad * 8];
      al[mi] = *(const short8*)&Al[cur][wm + mi * 16 + l15][quad * 8];
    }
#pragma unroll
    for (int ni = 0; ni < 4; ++ni) {
      bh[ni] = *(const short8*)&Bh[cur][wn + ni * 16 + l15][quad * 8];
      bl[ni] = *(const short8*)&Bl[cur][wn + ni * 16 + l15][quad * 8];
    }
    __builtin_amdgcn_s_setprio(1);
#pragma unroll
    for (int mi = 0; mi < 4; ++mi)
#pragma unroll
      for (int ni = 0; ni < 4; ++ni) {
        acc[mi][ni] = __builtin_amdgcn_mfma_f32_16x16x32_bf16(
            ah[mi], bh[ni], acc[mi][ni], 0, 0, 0);
        acc[mi][ni] = __builtin_amdgcn_mfma_f32_16x16x32_bf16(
            ah[mi], bl[ni], acc[mi][ni], 0, 0, 0);
        acc[mi][ni] = __builtin_amdgcn_mfma_f32_16x16x32_bf16(
            al[mi], bh[ni], acc[mi][ni], 0, 0, 0);
      }
    __builtin_amdgcn_s_setprio(0);

    // all ds_reads of buf[cur] are consumed by the MFMAs above (compiler
    // lgkmcnt); drain for safety, then barrier before buf[cur] can be
    // overwritten by next iteration's stage.
    __builtin_amdgcn_sched_barrier(0);
    asm volatile("s_waitcnt lgkmcnt(0)" ::: "memory");
    __builtin_amdgcn_s_barrier();
    __builtin_amdgcn_sched_barrier(0);
    cur ^= 1;
  }

  float bb[4];
#pragma unroll
  for (int ni = 0; ni < 4; ++ni) bb[ni] = bias[col0 + wn + ni * 16 + l15];
#pragma unroll
  for (int mi = 0; mi < 4; ++mi)
#pragma unroll
    for (int r = 0; r < 4; ++r) {
      const int row = row0 + wm + mi * 16 + quad * 4 + r;
      const float rm = ROWMASK ? rowmask[row] : 1.f;
#pragma unroll
      for (int ni = 0; ni < 4; ++ni) {
        const int col = col0 + wn + ni * 16 + l15;
        float v = acc[mi][ni][r] + bb[ni];
        if (SPLITOUT) {
          ushort vh, vl;
          bsplit(v, vh, vl);
          Ch[(size_t)row * Nc + col] = vh;
          Cl[(size_t)row * Nc + col] = vl;
        } else {
          if (ROWMASK) v *= rm;
          C[(size_t)row * Nc + col] = v;
        }
      }
    }
}

// ---------------------------------------------------------------------------
// MFMA flash attention. Block = (b, h, 64 q-rows); 4 waves x 16 rows.
// ---------------------------------------------------------------------------
__global__ __launch_bounds__(256) void attn_mfma_kernel(
    const ushort* __restrict__ Qh, const ushort* __restrict__ Ql,
    const ushort* __restrict__ Kh, const ushort* __restrict__ Kl,
    const ushort* __restrict__ Vth, const ushort* __restrict__ Vtl,
    const unsigned char* __restrict__ kvmask, const float* __restrict__ tsmask,
    float* __restrict__ outv, float* __restrict__ scores_out) {
  __shared__ __align__(16) ushort sm[24576];  // 48 KB
  ushort* KHT = sm;            // [64 rows(n)][64 e] swizzled
  ushort* KLT = sm + 4096;
  ushort* VTH = sm + 8192;     // [64 rows(e)][64 n] swizzled
  ushort* VTL = sm + 12288;
  ushort* QHT = sm + 16384;    // [64 rows(m)][64 e] swizzled (dead after frag read)
  ushort* QLT = sm + 20480;

  const int t = threadIdx.x, lane = t & 63, wv = t >> 6;
  const int l15 = lane & 15, quad = lane >> 4;
  const int blk = blockIdx.x;          // b*128 + h*8 + mt
  const int mt = blk & 7;
  const int h  = (blk >> 3) & 15;
  const int b  = blk >> 7;
  const int m0 = mt * 64;
  const int lrow = lane >> 3, lch = lane & 7;
  const int gch8 = (lch ^ (lrow & 7)) * 8;  // swizzled 16B-chunk, ushort offset

  // ---- stage Q tile (wave wv: rows wv*16..+15), hi and lo ----
#pragma unroll
  for (int i = 0; i < 2; ++i) {
    const int rr = wv * 16 + i * 8;   // wave-uniform LDS row base
    const size_t g = (size_t)(b * M_ + m0 + rr + lrow) * HE + h * 64 + gch8;
    gld16(Qh + g, &QHT[rr * 64]);
    gld16(Ql + g, &QLT[rr * 64]);
  }
  __syncthreads();

  short8 qh[2], ql[2];
#pragma unroll
  for (int ks = 0; ks < 2; ++ks) {
    const int row = wv * 16 + l15;
    const int off = row * 64 + (((ks * 4 + quad) ^ (row & 7)) << 3);
    qh[ks] = *(const short8*)&QHT[off];
    ql[ks] = *(const short8*)&QLT[off];
  }
  __builtin_amdgcn_s_waitcnt(0);  // Q frag reads complete before Pu aliases region

  uint* Pu = (uint*)(sm + 16384) + wv * 1024;  // per-wave P, packed hi|lo

  float tsm_v[4];
#pragma unroll
  for (int r = 0; r < 4; ++r)
    tsm_v[r] = tsmask[b * M_ + m0 + wv * 16 + quad * 4 + r];

  float m_i[4] = {-INFINITY, -INFINITY, -INFINITY, -INFINITY};
  float l_i[4] = {0.f, 0.f, 0.f, 0.f};
  f32x4 acc[4];
#pragma unroll
  for (int es = 0; es < 4; ++es) acc[es] = {0.f, 0.f, 0.f, 0.f};

  for (int nc = 0; nc < 16; ++nc) {
    const int n0 = nc * 64;
    __syncthreads();  // prev iter's LDS reads done (iter0: Q frag reads done)
    // ---- stage K rows / V^T rows (wave wv: rows wv*16..+15 of each) ----
#pragma unroll
    for (int i = 0; i < 2; ++i) {
      const int rr = wv * 16 + i * 8;
      const size_t gk = (size_t)(b * N_ + n0 + rr + lrow) * HE + h * 64 + gch8;
      const size_t gv = (size_t)((b * H_ + h) * 64 + rr + lrow) * N_ + n0 + gch8;
      gld16(Kh + gk, &KHT[rr * 64]);
      gld16(Kl + gk, &KLT[rr * 64]);
      gld16(Vth + gv, &VTH[rr * 64]);
      gld16(Vtl + gv, &VTL[rr * 64]);
    }
    __syncthreads();  // drains vmcnt

    // ---- S = Q K^T (split3) ----
    f32x4 s[4];
#pragma unroll
    for (int ns = 0; ns < 4; ++ns) {
      s[ns] = {0.f, 0.f, 0.f, 0.f};
#pragma unroll
      for (int ks = 0; ks < 2; ++ks) {
        const int row = ns * 16 + l15;
        const int off = row * 64 + (((ks * 4 + quad) ^ (row & 7)) << 3);
        const short8 kh = *(const short8*)&KHT[off];
        const short8 kl = *(const short8*)&KLT[off];
        s[ns] = __builtin_amdgcn_mfma_f32_16x16x32_bf16(qh[ks], kh, s[ns], 0, 0, 0);
        s[ns] = __builtin_amdgcn_mfma_f32_16x16x32_bf16(qh[ks], kl, s[ns], 0, 0, 0);
        s[ns] = __builtin_amdgcn_mfma_f32_16x16x32_bf16(ql[ks], kh, s[ns], 0, 0, 0);
      }
    }

    // ---- scale + mask ----
    bool km[4];
#pragma unroll
    for (int ns = 0; ns < 4; ++ns)
      km[ns] = kvmask[b * N_ + n0 + ns * 16 + l15] != 0;
    float sc[4][4];  // [reg r][ns]
#pragma unroll
    for (int ns = 0; ns < 4; ++ns)
#pragma unroll
      for (int r = 0; r < 4; ++r)
        sc[r][ns] = km[ns] ? -INFINITY : s[ns][r] * 0.125f;

    // ---- scores_for_log ----
#pragma unroll
    for (int r = 0; r < 4; ++r) {
      const size_t base =
          ((size_t)(b * H_ + h) * M_ + m0 + wv * 16 + quad * 4 + r) * N_ + n0;
      const bool vr = tsm_v[r] != 0.f;
#pragma unroll
      for (int ns = 0; ns < 4; ++ns)
        scores_out[base + ns * 16 + l15] =
            (vr && !km[ns]) ? sc[r][ns] : NEG_BIG;
    }

    // ---- online softmax + P pack to LDS ----
#pragma unroll
    for (int r = 0; r < 4; ++r) {
      float cm = fmaxf(fmaxf(sc[r][0], sc[r][1]), fmaxf(sc[r][2], sc[r][3]));
#pragma unroll
      for (int o = 1; o < 16; o <<= 1) cm = fmaxf(cm, __shfl_xor(cm, o));
      const float nm = fmaxf(m_i[r], cm);
      const float alpha = (m_i[r] == -INFINITY) ? 0.f : __expf(m_i[r] - nm);
      float ps = 0.f;
      const int pr = quad * 4 + r;
#pragma unroll
      for (int ns = 0; ns < 4; ++ns) {
        const float p = (sc[r][ns] == -INFINITY) ? 0.f : __expf(sc[r][ns] - nm);
        ps += p;
        ushort ph_, pl_;
        bsplit(p, ph_, pl_);
        const int c = ns * 16 + l15;
        Pu[pr * 64 + (((c >> 2) ^ (pr & 7)) << 2) + (c & 3)] = pk(ph_, pl_);
      }
#pragma unroll
      for (int o = 1; o < 16; o <<= 1) ps += __shfl_xor(ps, o);
      l_i[r] = l_i[r] * alpha + ps;
      m_i[r] = nm;
#pragma unroll
      for (int es = 0; es < 4; ++es) acc[es][r] *= alpha;
    }

    // ---- PV (split3); P A-frag from packed LDS, V^T B-frag ----
#pragma unroll
    for (int ks = 0; ks < 2; ++ks) {
      const int c0 = ks * 8 + quad * 2;
      const uint* pb = &Pu[l15 * 64];
      const uint4 u0 = *(const uint4*)&pb[(c0 ^ (l15 & 7)) << 2];
      const uint4 u1 = *(const uint4*)&pb[((c0 + 1) ^ (l15 & 7)) << 2];
      short8 ph, pl;
      const uint* up0 = (const uint*)&u0;
      const uint* up1 = (const uint*)&u1;
#pragma unroll
      for (int j = 0; j < 4; ++j) {
        ph[j] = (short)(up0[j] & 0xffffu); pl[j] = (short)(up0[j] >> 16);
        ph[4 + j] = (short)(up1[j] & 0xffffu); pl[4 + j] = (short)(up1[j] >> 16);
      }
#pragma unroll
      for (int es = 0; es < 4; ++es) {
        const int row = es * 16 + l15;
        const int off = row * 64 + (((ks * 4 + quad) ^ (row & 7)) << 3);
        const short8 vh = *(const short8*)&VTH[off];
        const short8 vl = *(const short8*)&VTL[off];
        acc[es] = __builtin_amdgcn_mfma_f32_16x16x32_bf16(ph, vh, acc[es], 0, 0, 0);
        acc[es] = __builtin_amdgcn_mfma_f32_16x16x32_bf16(ph, vl, acc[es], 0, 0, 0);
        acc[es] = __builtin_amdgcn_mfma_f32_16x16x32_bf16(pl, vh, acc[es], 0, 0, 0);
      }
    }
  }

  // ---- epilogue: out_v = acc / l ----
#pragma unroll
  for (int r = 0; r < 4; ++r) {
    const float inv = (l_i[r] > 0.f) ? 1.f / l_i[r] : 0.f;
    const int grow = b * M_ + m0 + wv * 16 + quad * 4 + r;
#pragma unroll
    for (int es = 0; es < 4; ++es)
      outv[(size_t)grow * HE + h * 64 + es * 16 + l15] = acc[es][r] * inv;
  }
}

// ---------------------------------------------------------------------------
extern "C" void kernel_launch(void* const* d_in, const int* in_sizes, int n_in,
                              void* d_out, int out_size, void* d_ws,
                              size_t ws_size, hipStream_t stream) {
  const float* ts  = (const float*)d_in[0];
  const float* kv  = (const float*)d_in[1];
  const float* tsm = (const float*)d_in[2];
  const unsigned char* kvm = (const unsigned char*)d_in[3];
  const float* Wq = (const float*)d_in[4];
  const float* bq = (const float*)d_in[5];
  const float* Wk = (const float*)d_in[6];
  const float* bk = (const float*)d_in[7];
  const float* Wv = (const float*)d_in[8];
  const float* bv = (const float*)d_in[9];
  const float* Wo = (const float*)d_in[10];
  const float* bo = (const float*)d_in[11];

  float* out        = (float*)d_out;
  float* scores_out = out + (size_t)B_ * M_ * DLLM;

  char* ws = (char*)d_ws;
  constexpr size_t MB = 1024 * 1024;

  if (ws_size >= 260 * MB) {
    // ---------- pre-split path (A operands staged as bf16 hi/lo) ----------
    ushort* Kvh  = (ushort*)(ws);
    ushort* Kvl  = (ushort*)(ws + 64 * MB);
    float*  Vf   = (float*)(ws + 128 * MB);
    ushort* Khp  = (ushort*)(ws + 160 * MB);
    ushort* Klp  = (ushort*)(ws + 176 * MB);
    ushort* Qhp  = (ushort*)(ws + 192 * MB);
    ushort* Qlp  = (ushort*)(ws + 200 * MB);
    ushort* Tsh  = (ushort*)(ws + 208 * MB);
    ushort* Tsl  = (ushort*)(ws + 216 * MB);
    ushort* Wqh  = (ushort*)(ws + 224 * MB);
    ushort* Wql  = (ushort*)(ws + 226 * MB);
    ushort* Wkh  = (ushort*)(ws + 228 * MB);
    ushort* Wkl  = (ushort*)(ws + 236 * MB);
    ushort* Wvh  = (ushort*)(ws + 244 * MB);
    ushort* Wvl  = (ushort*)(ws + 252 * MB);
    // aliases valid once predecessors are dead (stream-ordered)
    ushort* Vthp  = (ushort*)(ws);
    ushort* Vtlp  = (ushort*)(ws + 16 * MB);
    ushort* outvh = (ushort*)(ws + 32 * MB);
    ushort* outvl = (ushort*)(ws + 40 * MB);
    ushort* Woh   = (ushort*)(ws + 64 * MB);
    ushort* Wol   = (ushort*)(ws + 72 * MB);
    float*  outv  = (float*)(ws + 128 * MB);

    // input pre-splits
    {
      const int n8_ts = (B_ * M_ * DTS) / 8;     // 512K
      asplit_kernel<<<dim3(n8_ts / 256), 256, 0, stream>>>(ts, Tsh, Tsl, n8_ts);
      const int n8_kv = (B_ * N_ * DLLM) / 8;    // 4M
      asplit_kernel<<<dim3(n8_kv / 256), 256, 0, stream>>>(kv, Kvh, Kvl, n8_kv);
    }

    // weight transpose+split
    tsplit_kernel<<<dim3(HE / 32, DTS / 32), 256, 0, stream>>>(Wq, Wqh, Wql, DTS, HE);
    tsplit_kernel<<<dim3(HE / 32, DLLM / 32), 256, 0, stream>>>(Wk, Wkh, Wkl, DLLM, HE);
    tsplit_kernel<<<dim3(HE / 32, DLLM / 32), 256, 0, stream>>>(Wv, Wvh, Wvl, DLLM, HE);

    // projections (both operands pre-split); 1D grid, XCD-aware decode
    gemm_bb_kernel<false, true><<<dim3((HE / 128) * ((B_ * M_) / 128)), 256, 0, stream>>>(
        Tsh, Tsl, Wqh, Wql, bq, nullptr, nullptr, Qhp, Qlp, DTS, HE, HE / 128);
    gemm_bb_kernel<false, true><<<dim3((HE / 128) * ((B_ * N_) / 128)), 256, 0, stream>>>(
        Kvh, Kvl, Wkh, Wkl, bk, nullptr, nullptr, Khp, Klp, DLLM, HE, HE / 128);
    gemm_bb_kernel<false, false><<<dim3((HE / 128) * ((B_ * N_) / 128)), 256, 0, stream>>>(
        Kvh, Kvl, Wvh, Wvl, bv, nullptr, Vf, nullptr, nullptr, DLLM, HE, HE / 128);

    // V^T split prep (Kv regions dead now; writes into [0,32))
    vtprep_kernel<<<dim3(B_ * H_ * 16), 256, 0, stream>>>(Vf, Vthp, Vtlp);

    // MFMA flash attention (+ scores_for_log); writes outv fp32 over dead Vf
    attn_mfma_kernel<<<dim3(B_ * H_ * (M_ / 64)), 256, 0, stream>>>(
        Qhp, Qlp, Khp, Klp, Vthp, Vtlp, kvm, tsm, outv, scores_out);

    // split attn output for pre-split O-GEMM
    {
      const int n8_o = (B_ * M_ * HE) / 8;       // 512K
      asplit_kernel<<<dim3(n8_o / 256), 256, 0, stream>>>(outv, outvh, outvl, n8_o);
    }

    // output projection
    tsplit_kernel<<<dim3(DLLM / 32, HE / 32), 256, 0, stream>>>(Wo, Woh, Wol, HE, DLLM);
    gemm_bb_kernel<true, false><<<dim3((DLLM / 128) * ((B_ * M_) / 128)), 256, 0, stream>>>(
        outvh, outvl, Woh, Wol, bo, tsm, out, nullptr, nullptr, HE, DLLM, DLLM / 128);
  } else {
    // ---------- fallback: exact verified baseline path (116 MB) ----------
    float*  Vf   = (float*)(ws);
    float*  outv = (float*)(ws);
    ushort* Qhp  = (ushort*)(ws + 32 * MB);
    ushort* Qlp  = (ushort*)(ws + 40 * MB);
    ushort* Khp  = (ushort*)(ws + 48 * MB);
    ushort* Klp  = (ushort*)(ws + 64 * MB);
    ushort* Wqh  = (ushort*)(ws + 80 * MB);
    ushort* Wql  = (ushort*)(ws + 82 * MB);
    ushort* Wkh  = (ushort*)(ws + 84 * MB);
    ushort* Wkl  = (ushort*)(ws + 92 * MB);
    ushort* Wvh  = (ushort*)(ws + 100 * MB);
    ushort* Wvl  = (ushort*)(ws + 108 * MB);
    ushort* Vthp = (ushort*)(ws + 84 * MB);
    ushort* Vtlp = (ushort*)(ws + 100 * MB);
    ushort* Woh  = (ushort*)(ws + 48 * MB);
    ushort* Wol  = (ushort*)(ws + 56 * MB);

    tsplit_kernel<<<dim3(HE / 32, DTS / 32), 256, 0, stream>>>(Wq, Wqh, Wql, DTS, HE);
    tsplit_kernel<<<dim3(HE / 32, DLLM / 32), 256, 0, stream>>>(Wk, Wkh, Wkl, DLLM, HE);
    tsplit_kernel<<<dim3(HE / 32, DLLM / 32), 256, 0, stream>>>(Wv, Wvh, Wvl, DLLM, HE);

    gemm_split3_kernel<false, true><<<dim3(HE / 128, (B_ * M_) / 128), 256, 0, stream>>>(
        ts, Wqh, Wql, bq, nullptr, nullptr, Qhp, Qlp, DTS, HE);
    gemm_split3_kernel<false, true><<<dim3(HE / 128, (B_ * N_) / 128), 256, 0, stream>>>(
        kv, Wkh, Wkl, bk, nullptr, nullptr, Khp, Klp, DLLM, HE);
    gemm_split3_kernel<false, false><<<dim3(HE / 128, (B_ * N_) / 128), 256, 0, stream>>>(
        kv, Wvh, Wvl, bv, nullptr, Vf, nullptr, nullptr, DLLM, HE);

    vtprep_kernel<<<dim3(B_ * H_ * 16), 256, 0, stream>>>(Vf, Vthp, Vtlp);

    attn_mfma_kernel<<<dim3(B_ * H_ * (M_ / 64)), 256, 0, stream>>>(
        Qhp, Qlp, Khp, Klp, Vthp, Vtlp, kvm, tsm, outv, scores_out);

    tsplit_kernel<<<dim3(DLLM / 32, HE / 32), 256, 0, stream>>>(Wo, Woh, Wol, HE, DLLM);
    gemm_split3_kernel<true, false><<<dim3(DLLM / 128, (B_ * M_) / 128), 256, 0, stream>>>(
        outv, Woh, Wol, bo, tsm, out, nullptr, nullptr, HE, DLLM);
  }
}